// Round 2
// baseline (951.179 us; speedup 1.0000x reference)
//
#include <hip/hip_runtime.h>
#include <math.h>

// ---------------------------------------------------------------------------
// DAHead: B=8, Cin=512, Ci=128, H=W=64, N=4096, Ck=16, NC=19.
// R7: conv family restructured for ILP at fixed (grid-capped) occupancy:
//  - W fragments loaded per-lane straight from wpack (global, L2-hot) — no W
//    LDS stage at all (merged LDS 72.2 -> 33.8 KB).
//  - X double-buffered in LDS, ONE barrier per chunk: barrier; prefetch next
//    chunk to regs; MFMA on cur; decompose+ds_write to cur^1.
//  - halo columns / OOB rows zeroed once (always zero), interior staged
//    1 position/thread.
//  - cam_feat emits hi/lo bf16 directly; conv2c consumes bf16 (no fp32 camf).
// ws (byte offsets):
//   bufA@0 (16MB fp32)  bufB@16M (16MB fp32)
//   vb@32M (8MB bf16)   egy_part@40M (4MB fp32)   [both dead before conv2p]
//   bufD@32M (16MB fp32, conv2p out)
//   bh@48M, bl@56M (8MB bf16 each) -> pam_bf@48M -> c2h@48M, c2l@56M
//   qt@64M, kt@65M, rowmax@66M, egy@66M+128K
//   wp1@67M, wc1h, wc1l (1.125MB each), wp2, wc2h, wc2l (288KB each)
// ---------------------------------------------------------------------------

typedef __attribute__((ext_vector_type(8)))  short short8;
typedef __attribute__((ext_vector_type(16))) float f32x16;

__device__ inline unsigned short f2bf(float f) {
    union { float f; unsigned u; } v; v.f = f;
    unsigned r = v.u + 0x7fffu + ((v.u >> 16) & 1u);   // RNE
    return (unsigned short)(r >> 16);
}
__device__ inline float bf2f(unsigned short h) {
    union { unsigned u; float f; } v; v.u = ((unsigned)h) << 16;
    return v.f;
}

// ---- weight prepack: W[co][cin][9] fp32 ->
//      wpack[chunk][tap][g(=ci>>3)][co128][ci8]  (bf16) ----------------------
__global__ __launch_bounds__(256) void wpack_kernel(
    const float* __restrict__ W, unsigned short* __restrict__ wp, int Cin, int total)
{
    int idx = blockIdx.x * 256 + threadIdx.x;
    if (idx >= total) return;
    int chunk = idx / 18432;
    int rem   = idx - chunk * 18432;
    int tap   = rem >> 11;
    int rem2  = rem & 2047;
    int g     = rem2 >> 10;
    int co    = (rem2 >> 3) & 127;
    int ci8   = rem2 & 7;
    int cin   = (chunk << 4) + (g << 3) + ci8;
    wp[idx] = f2bf(W[((size_t)co * Cin + cin) * 9 + tap]);
}

__global__ __launch_bounds__(256) void wpack_split_kernel(
    const float* __restrict__ W, unsigned short* __restrict__ wph,
    unsigned short* __restrict__ wpl, int Cin, int total)
{
    int idx = blockIdx.x * 256 + threadIdx.x;
    if (idx >= total) return;
    int chunk = idx / 18432;
    int rem   = idx - chunk * 18432;
    int tap   = rem >> 11;
    int rem2  = rem & 2047;
    int g     = rem2 >> 10;
    int co    = (rem2 >> 3) & 127;
    int ci8   = rem2 & 7;
    int cin   = (chunk << 4) + (g << 3) + ci8;
    float w = W[((size_t)co * Cin + cin) * 9 + tap];
    unsigned short hi = f2bf(w);
    wph[idx] = hi;
    wpl[idx] = f2bf(w - bf2f(hi));
}

// ---- FUSED conv1: plain (Wp1 -> bufA) + hilo (Wc1 -> bufB,bh,bl) ----------
// fp32 input, inline hi/lo split. X double-buffered, W in registers.
// grid (32, 2, 8), 256 thr. LDS 33792 B.
__global__ __launch_bounds__(256) void conv3x3_merged(
    const float* __restrict__ xin,
    const unsigned short* __restrict__ wpp,
    const unsigned short* __restrict__ wph, const unsigned short* __restrict__ wpl,
    const float* __restrict__ bnp, const float* __restrict__ bnc,
    float* __restrict__ outP, float* __restrict__ outC,
    unsigned short* __restrict__ outh, unsigned short* __restrict__ outl)
{
    const int t   = threadIdx.x;
    const int w   = t >> 6;
    const int wy  = w >> 1;
    const int wx  = w & 1;
    const int ln  = t & 63;
    const int l31 = ln & 31;
    const int g   = ln >> 5;
    const int y0  = blockIdx.x << 1;
    const int co0 = blockIdx.y << 6;
    const int b   = blockIdx.z;

    // staging: one interior position per thread; halos stay zero forever
    const int sr   = t >> 6;           // row 0..3  (gy = y0-1+sr)
    const int sx   = t & 63;           // gx
    const int sgy  = y0 - 1 + sr;
    const bool sv  = (unsigned)sgy < 64u;
    const int spid = sr * 66 + sx + 1;

    __shared__ __align__(16) unsigned short Xh[2][4224];   // [buf][g*2112 + pid*8]
    __shared__ __align__(16) unsigned short Xo[2][4224];   // 33792 B total

    for (int i = t; i < 1056; i += 256) {
        uint4 z; z.x = 0; z.y = 0; z.z = 0; z.w = 0;
        ((uint4*)Xh)[i] = z;
        ((uint4*)Xo)[i] = z;
    }

    const int co = co0 + (wy << 5) + l31;
    const unsigned short* wPb = wpp + (size_t)(g << 10) + ((size_t)co << 3);
    const unsigned short* wHb = wph + (size_t)(g << 10) + ((size_t)co << 3);
    const unsigned short* wLb = wpl + (size_t)(g << 10) + ((size_t)co << 3);
    const float* xsrc = xin + ((size_t)b << 21) + (sgy << 6) + sx;

    const f32x16 zero = {0,0,0,0,0,0,0,0,0,0,0,0,0,0,0,0};
    f32x16 ap0 = zero, ap1 = zero, ac0 = zero, ac1 = zero;

    float xv[16];
    if (sv) {
#pragma unroll
        for (int c = 0; c < 16; c++) xv[c] = xsrc[(size_t)c << 12];
    }
    __syncthreads();   // zero-init done

    // prologue: stage chunk 0 into buf 0
    if (sv) {
        unsigned short th[16], tl[16];
#pragma unroll
        for (int c = 0; c < 16; c++) {
            unsigned short hi = f2bf(xv[c]);
            th[c] = hi; tl[c] = f2bf(xv[c] - bf2f(hi));
        }
        *(uint4*)&Xh[0][spid << 3]          = ((uint4*)th)[0];
        *(uint4*)&Xh[0][2112 + (spid << 3)] = ((uint4*)th)[1];
        *(uint4*)&Xo[0][spid << 3]          = ((uint4*)tl)[0];
        *(uint4*)&Xo[0][2112 + (spid << 3)] = ((uint4*)tl)[1];
    }

    int cur = 0;
    for (int ch = 0; ch < 32; ++ch) {
        __syncthreads();
        const bool pf = (ch < 31);
        if (pf && sv) {
#pragma unroll
            for (int c = 0; c < 16; c++)
                xv[c] = xsrc[((size_t)(ch + 1) << 16) + ((size_t)c << 12)];
        }
        const size_t wo = (size_t)ch * 18432;
#pragma unroll 3
        for (int tap = 0; tap < 9; ++tap) {
            const int dy = tap / 3, dx = tap - dy * 3;
            const int row = wx + dy;
            const int xi = (g ? 2112 : 0) + (((row * 66) + l31 + dx) << 3);
            short8 vap = *(const short8*)(wPb + wo + tap * 2048);
            short8 vah = *(const short8*)(wHb + wo + tap * 2048);
            short8 val = *(const short8*)(wLb + wo + tap * 2048);
            short8 b0h = *(const short8*)&Xh[cur][xi];
            short8 b1h = *(const short8*)&Xh[cur][xi + 256];
            short8 b0l = *(const short8*)&Xo[cur][xi];
            short8 b1l = *(const short8*)&Xo[cur][xi + 256];
            ap0 = __builtin_amdgcn_mfma_f32_32x32x16_bf16(vap, b0h, ap0, 0, 0, 0);
            ap1 = __builtin_amdgcn_mfma_f32_32x32x16_bf16(vap, b1h, ap1, 0, 0, 0);
            ac0 = __builtin_amdgcn_mfma_f32_32x32x16_bf16(vah, b0h, ac0, 0, 0, 0);
            ac1 = __builtin_amdgcn_mfma_f32_32x32x16_bf16(vah, b1h, ac1, 0, 0, 0);
            ac0 = __builtin_amdgcn_mfma_f32_32x32x16_bf16(vah, b0l, ac0, 0, 0, 0);
            ac1 = __builtin_amdgcn_mfma_f32_32x32x16_bf16(vah, b1l, ac1, 0, 0, 0);
            ac0 = __builtin_amdgcn_mfma_f32_32x32x16_bf16(val, b0h, ac0, 0, 0, 0);
            ac1 = __builtin_amdgcn_mfma_f32_32x32x16_bf16(val, b1h, ac1, 0, 0, 0);
        }
        if (pf && sv) {
            unsigned short th[16], tl[16];
#pragma unroll
            for (int c = 0; c < 16; c++) {
                unsigned short hi = f2bf(xv[c]);
                th[c] = hi; tl[c] = f2bf(xv[c] - bf2f(hi));
            }
            const int nb = cur ^ 1;
            *(uint4*)&Xh[nb][spid << 3]          = ((uint4*)th)[0];
            *(uint4*)&Xh[nb][2112 + (spid << 3)] = ((uint4*)th)[1];
            *(uint4*)&Xo[nb][spid << 3]          = ((uint4*)tl)[0];
            *(uint4*)&Xo[nb][2112 + (spid << 3)] = ((uint4*)tl)[1];
        }
        cur ^= 1;
    }

    const int y = y0 + wx;
#pragma unroll
    for (int j = 0; j < 2; j++) {
        const f32x16 aP = j ? ap1 : ap0;
        const f32x16 aC = j ? ac1 : ac0;
#pragma unroll
        for (int r = 0; r < 16; r++) {
            int c2 = co0 + (wy << 5) + (r & 3) + ((r >> 2) << 3) + (g << 2);
            int x  = (j << 5) + l31;
            size_t o = (((size_t)b * 128 + c2) << 12) + (y << 6) + x;
            float vp = fmaf(aP[r], bnp[c2], bnp[128 + c2]);
            vp = vp > 0.f ? vp : 0.f;
            outP[o] = vp;
            float vc = fmaf(aC[r], bnc[c2], bnc[128 + c2]);
            vc = vc > 0.f ? vc : 0.f;
            outC[o] = vc;
            unsigned short hi = f2bf(vc);
            outh[o] = hi;
            outl[o] = f2bf(vc - bf2f(hi));
        }
    }
}

// ---- plain 3x3 conv, bf16 input (conv2p). X dbuf, W regs. grid (32,2,8) ---
__global__ __launch_bounds__(256) void conv3x3_bf(
    const unsigned short* __restrict__ xin, int Cin,
    const unsigned short* __restrict__ wpk, const float* __restrict__ bn,
    float* __restrict__ out_f32)
{
    const int t   = threadIdx.x;
    const int w   = t >> 6;
    const int wy  = w >> 1;
    const int wx  = w & 1;
    const int ln  = t & 63;
    const int l31 = ln & 31;
    const int g   = ln >> 5;
    const int y0  = blockIdx.x << 1;
    const int co0 = blockIdx.y << 6;
    const int b   = blockIdx.z;

    const int sr   = t >> 6;
    const int sx   = t & 63;
    const int sgy  = y0 - 1 + sr;
    const bool sv  = (unsigned)sgy < 64u;
    const int spid = sr * 66 + sx + 1;

    __shared__ __align__(16) unsigned short Xl[2][4224];   // 16896 B

    for (int i = t; i < 1056; i += 256) {
        uint4 z; z.x = 0; z.y = 0; z.z = 0; z.w = 0;
        ((uint4*)Xl)[i] = z;
    }

    const int co = co0 + (wy << 5) + l31;
    const unsigned short* wB = wpk + (size_t)(g << 10) + ((size_t)co << 3);
    const unsigned short* xsrc = xin + (((size_t)b * Cin) << 12) + (sgy << 6) + sx;

    const f32x16 zero = {0,0,0,0,0,0,0,0,0,0,0,0,0,0,0,0};
    f32x16 acc0 = zero, acc1 = zero;

    unsigned short xv[16];
    if (sv) {
#pragma unroll
        for (int c = 0; c < 16; c++) xv[c] = xsrc[(size_t)c << 12];
    }
    __syncthreads();

    if (sv) {
        *(uint4*)&Xl[0][spid << 3]          = ((uint4*)xv)[0];
        *(uint4*)&Xl[0][2112 + (spid << 3)] = ((uint4*)xv)[1];
    }

    const int nchunks = Cin >> 4;
    int cur = 0;
    for (int ch = 0; ch < nchunks; ++ch) {
        __syncthreads();
        const bool pf = (ch < nchunks - 1);
        if (pf && sv) {
#pragma unroll
            for (int c = 0; c < 16; c++)
                xv[c] = xsrc[((size_t)(ch + 1) << 16) + ((size_t)c << 12)];
        }
        const size_t wo = (size_t)ch * 18432;
#pragma unroll 3
        for (int tap = 0; tap < 9; ++tap) {
            const int dy = tap / 3, dx = tap - dy * 3;
            const int row = wx + dy;
            const int xi = (g ? 2112 : 0) + (((row * 66) + l31 + dx) << 3);
            short8 a  = *(const short8*)(wB + wo + tap * 2048);
            short8 b0 = *(const short8*)&Xl[cur][xi];
            short8 b1 = *(const short8*)&Xl[cur][xi + 256];
            acc0 = __builtin_amdgcn_mfma_f32_32x32x16_bf16(a, b0, acc0, 0, 0, 0);
            acc1 = __builtin_amdgcn_mfma_f32_32x32x16_bf16(a, b1, acc1, 0, 0, 0);
        }
        if (pf && sv) {
            const int nb = cur ^ 1;
            *(uint4*)&Xl[nb][spid << 3]          = ((uint4*)xv)[0];
            *(uint4*)&Xl[nb][2112 + (spid << 3)] = ((uint4*)xv)[1];
        }
        cur ^= 1;
    }

    const int y = y0 + wx;
#pragma unroll
    for (int j = 0; j < 2; j++) {
        const f32x16 a = j ? acc1 : acc0;
#pragma unroll
        for (int r = 0; r < 16; r++) {
            int c2 = co0 + (wy << 5) + (r & 3) + ((r >> 2) << 3) + (g << 2);
            int x  = (j << 5) + l31;
            float v = fmaf(a[r], bn[c2], bn[128 + c2]);
            v = v > 0.f ? v : 0.f;
            out_f32[(((size_t)b * 128 + c2) << 12) + (y << 6) + x] = v;
        }
    }
}

// ---- hilo 3x3 conv, pre-split bf16 inputs (conv2c). grid (32,2,8) ---------
__global__ __launch_bounds__(256) void conv3x3_hilo_bf(
    const unsigned short* __restrict__ xhg, const unsigned short* __restrict__ xlg,
    int Cin, const unsigned short* __restrict__ wph, const unsigned short* __restrict__ wpl,
    const float* __restrict__ bn, float* __restrict__ out_f32)
{
    const int t   = threadIdx.x;
    const int w   = t >> 6;
    const int wy  = w >> 1;
    const int wx  = w & 1;
    const int ln  = t & 63;
    const int l31 = ln & 31;
    const int g   = ln >> 5;
    const int y0  = blockIdx.x << 1;
    const int co0 = blockIdx.y << 6;
    const int b   = blockIdx.z;

    const int sr   = t >> 6;
    const int sx   = t & 63;
    const int sgy  = y0 - 1 + sr;
    const bool sv  = (unsigned)sgy < 64u;
    const int spid = sr * 66 + sx + 1;

    __shared__ __align__(16) unsigned short Xh[2][4224];
    __shared__ __align__(16) unsigned short Xo[2][4224];   // 33792 B

    for (int i = t; i < 1056; i += 256) {
        uint4 z; z.x = 0; z.y = 0; z.z = 0; z.w = 0;
        ((uint4*)Xh)[i] = z;
        ((uint4*)Xo)[i] = z;
    }

    const int co = co0 + (wy << 5) + l31;
    const unsigned short* wHb = wph + (size_t)(g << 10) + ((size_t)co << 3);
    const unsigned short* wLb = wpl + (size_t)(g << 10) + ((size_t)co << 3);
    const unsigned short* hsrc = xhg + (((size_t)b * Cin) << 12) + (sgy << 6) + sx;
    const unsigned short* lsrc = xlg + (((size_t)b * Cin) << 12) + (sgy << 6) + sx;

    const f32x16 zero = {0,0,0,0,0,0,0,0,0,0,0,0,0,0,0,0};
    f32x16 acc0 = zero, acc1 = zero;

    unsigned short hv[16], lv[16];
    if (sv) {
#pragma unroll
        for (int c = 0; c < 16; c++) { hv[c] = hsrc[(size_t)c << 12]; lv[c] = lsrc[(size_t)c << 12]; }
    }
    __syncthreads();

    if (sv) {
        *(uint4*)&Xh[0][spid << 3]          = ((uint4*)hv)[0];
        *(uint4*)&Xh[0][2112 + (spid << 3)] = ((uint4*)hv)[1];
        *(uint4*)&Xo[0][spid << 3]          = ((uint4*)lv)[0];
        *(uint4*)&Xo[0][2112 + (spid << 3)] = ((uint4*)lv)[1];
    }

    const int nchunks = Cin >> 4;
    int cur = 0;
    for (int ch = 0; ch < nchunks; ++ch) {
        __syncthreads();
        const bool pf = (ch < nchunks - 1);
        if (pf && sv) {
#pragma unroll
            for (int c = 0; c < 16; c++) {
                hv[c] = hsrc[((size_t)(ch + 1) << 16) + ((size_t)c << 12)];
                lv[c] = lsrc[((size_t)(ch + 1) << 16) + ((size_t)c << 12)];
            }
        }
        const size_t wo = (size_t)ch * 18432;
#pragma unroll 3
        for (int tap = 0; tap < 9; ++tap) {
            const int dy = tap / 3, dx = tap - dy * 3;
            const int row = wx + dy;
            const int xi = (g ? 2112 : 0) + (((row * 66) + l31 + dx) << 3);
            short8 ah  = *(const short8*)(wHb + wo + tap * 2048);
            short8 al  = *(const short8*)(wLb + wo + tap * 2048);
            short8 b0h = *(const short8*)&Xh[cur][xi];
            short8 b1h = *(const short8*)&Xh[cur][xi + 256];
            short8 b0l = *(const short8*)&Xo[cur][xi];
            short8 b1l = *(const short8*)&Xo[cur][xi + 256];
            acc0 = __builtin_amdgcn_mfma_f32_32x32x16_bf16(ah, b0h, acc0, 0, 0, 0);
            acc1 = __builtin_amdgcn_mfma_f32_32x32x16_bf16(ah, b1h, acc1, 0, 0, 0);
            acc0 = __builtin_amdgcn_mfma_f32_32x32x16_bf16(ah, b0l, acc0, 0, 0, 0);
            acc1 = __builtin_amdgcn_mfma_f32_32x32x16_bf16(ah, b1l, acc1, 0, 0, 0);
            acc0 = __builtin_amdgcn_mfma_f32_32x32x16_bf16(al, b0h, acc0, 0, 0, 0);
            acc1 = __builtin_amdgcn_mfma_f32_32x32x16_bf16(al, b1h, acc1, 0, 0, 0);
        }
        if (pf && sv) {
            const int nb = cur ^ 1;
            *(uint4*)&Xh[nb][spid << 3]          = ((uint4*)hv)[0];
            *(uint4*)&Xh[nb][2112 + (spid << 3)] = ((uint4*)hv)[1];
            *(uint4*)&Xo[nb][spid << 3]          = ((uint4*)lv)[0];
            *(uint4*)&Xo[nb][2112 + (spid << 3)] = ((uint4*)lv)[1];
        }
        cur ^= 1;
    }

    const int y = y0 + wx;
#pragma unroll
    for (int j = 0; j < 2; j++) {
        const f32x16 a = j ? acc1 : acc0;
#pragma unroll
        for (int r = 0; r < 16; r++) {
            int c2 = co0 + (wy << 5) + (r & 3) + ((r >> 2) << 3) + (g << 2);
            int x  = (j << 5) + l31;
            float v = fmaf(a[r], bn[c2], bn[128 + c2]);
            v = v > 0.f ? v : 0.f;
            out_f32[(((size_t)b * 128 + c2) << 12) + (y << 6) + x] = v;
        }
    }
}

// ---- CAM Gram via hi/lo MFMA, n-split partials. grid (16, 8, 8) -----------
__global__ __launch_bounds__(256) void cam_energy_mfma(
    const unsigned short* __restrict__ bh, const unsigned short* __restrict__ bl,
    float* __restrict__ egy_part)
{
    const int t   = threadIdx.x;
    const int w   = t >> 6;
    const int ln  = t & 63;
    const int l31 = ln & 31;
    const int g   = ln >> 5;
    const int i0  = (blockIdx.x >> 2) << 5;
    const int j0  = (blockIdx.x & 3) << 5;
    const int nseg = blockIdx.y;
    const int b   = blockIdx.z;

    __shared__ float red[4][64][17];

    const f32x16 zero = {0,0,0,0,0,0,0,0,0,0,0,0,0,0,0,0};
    f32x16 acc = zero;
    const int nb = (nseg << 9) + (w << 7) + (g << 3);
    const size_t ri = ((size_t)b * 128 + i0 + l31) << 12;
    const size_t rj = ((size_t)b * 128 + j0 + l31) << 12;

#pragma unroll
    for (int c = 0; c < 8; c++) {
        const int n0 = nb + (c << 4);
        short8 ah  = *(const short8*)(bh + ri + n0);
        short8 al  = *(const short8*)(bl + ri + n0);
        short8 bhf = *(const short8*)(bh + rj + n0);
        short8 blf = *(const short8*)(bl + rj + n0);
        acc = __builtin_amdgcn_mfma_f32_32x32x16_bf16(ah, bhf, acc, 0, 0, 0);
        acc = __builtin_amdgcn_mfma_f32_32x32x16_bf16(ah, blf, acc, 0, 0, 0);
        acc = __builtin_amdgcn_mfma_f32_32x32x16_bf16(al, bhf, acc, 0, 0, 0);
    }
#pragma unroll
    for (int r = 0; r < 16; r++) red[w][ln][r] = acc[r];
    __syncthreads();

    const int lane = t & 63;
    const int rq   = t >> 6;
    float* base = egy_part + (((size_t)(nseg * 8 + b)) << 14);
#pragma unroll
    for (int e = 0; e < 4; e++) {
        const int reg = (rq << 2) + e;
        float v = red[0][lane][reg] + red[1][lane][reg]
                + red[2][lane][reg] + red[3][lane][reg];
        const int i = i0 + (reg & 3) + ((reg >> 2) << 3) + ((lane >> 5) << 2);
        base[i * 128 + j0 + (lane & 31)] = v;
    }
}

// ---- CAM softmax of (rowmax - e), fused 8-seg reduce. grid (8, 8) ---------
__global__ __launch_bounds__(256) void cam_softmax_fused(
    const float* __restrict__ egy_part, float* __restrict__ egy)
{
    const int b   = blockIdx.x;
    const int rg  = blockIdx.y;
    const int t   = threadIdx.x;
    const int row = (rg << 4) + (t >> 4);
    const int jg  = t & 15;

    float e[8];
#pragma unroll
    for (int jj = 0; jj < 8; jj++) e[jj] = 0.f;
    for (int seg = 0; seg < 8; seg++) {
        const float* p = egy_part + (((size_t)(seg * 8 + b)) << 14) + row * 128 + (jg << 3);
#pragma unroll
        for (int jj = 0; jj < 8; jj++) e[jj] += p[jj];
    }
    float mn = e[0];
#pragma unroll
    for (int jj = 1; jj < 8; jj++) mn = fminf(mn, e[jj]);
#pragma unroll
    for (int k = 1; k < 16; k <<= 1) mn = fminf(mn, __shfl_xor(mn, k));
    float s = 0.f;
#pragma unroll
    for (int jj = 0; jj < 8; jj++) { float p = __expf(mn - e[jj]); e[jj] = p; s += p; }
#pragma unroll
    for (int k = 1; k < 16; k <<= 1) s += __shfl_xor(s, k);
    const float inv = 1.f / s;
    float* orow = egy + ((size_t)b << 14) + row * 128 + (jg << 3);
#pragma unroll
    for (int jj = 0; jj < 8; jj++) orow[jj] = e[jj] * inv;
}

// ---- PAM Q/K producer ----
__global__ __launch_bounds__(256) void pam_qk_1x1(
    const float* __restrict__ A, const float* __restrict__ Wb, const float* __restrict__ bb,
    const float* __restrict__ Wc, const float* __restrict__ bc,
    unsigned short* __restrict__ qt, unsigned short* __restrict__ kt)
{
    __shared__ float wl[2 * 16 * 128];
    __shared__ float bl[32];
    const int t = threadIdx.x;
    const int n = (blockIdx.x << 8) + t;
    const int b = blockIdx.y;
    for (int idx = t; idx < 2048; idx += 256) { wl[idx] = Wb[idx]; wl[2048 + idx] = Wc[idx]; }
    if (t < 16) { bl[t] = bb[t]; bl[16 + t] = bc[t]; }
    __syncthreads();
    float ab[16], ac[16];
#pragma unroll
    for (int k = 0; k < 16; k++) { ab[k] = 0.f; ac[k] = 0.f; }
    for (int chn = 0; chn < 128; ++chn) {
        float a = A[(((size_t)b * 128 + chn) << 12) + n];
#pragma unroll
        for (int k = 0; k < 16; k++) {
            ab[k] = fmaf(wl[k * 128 + chn], a, ab[k]);
            ac[k] = fmaf(wl[2048 + k * 128 + chn], a, ac[k]);
        }
    }
    unsigned short uq[16], uk[16];
#pragma unroll
    for (int k = 0; k < 16; k++) {
        uq[k] = f2bf(ab[k] + bl[k]);
        uk[k] = f2bf(ac[k] + bl[16 + k]);
    }
    size_t row = (size_t)b * 4096 + n;
    ((uint4*)qt)[row * 2 + 0] = ((uint4*)uq)[0];
    ((uint4*)qt)[row * 2 + 1] = ((uint4*)uq)[1];
    ((uint4*)kt)[row * 2 + 0] = ((uint4*)uk)[0];
    ((uint4*)kt)[row * 2 + 1] = ((uint4*)uk)[1];
}

// ---- PAM V producer ----
__global__ __launch_bounds__(256) void pam_v_1x1(
    const float* __restrict__ A, const float* __restrict__ Wd, const float* __restrict__ bd,
    unsigned short* __restrict__ vb)
{
    __shared__ float wl[32 * 128];
    __shared__ float bl[32];
    const int t   = threadIdx.x;
    const int n   = (blockIdx.x << 8) + t;
    const int co0 = blockIdx.y << 5;
    const int b   = blockIdx.z;
    for (int idx = t; idx < 4096; idx += 256) {
        int c2 = idx >> 7, chv = idx & 127;
        wl[idx] = Wd[(co0 + c2) * 128 + chv];
    }
    if (t < 32) bl[t] = bd[co0 + t];
    __syncthreads();
    float acc[32];
#pragma unroll
    for (int k = 0; k < 32; k++) acc[k] = 0.f;
    for (int chn = 0; chn < 128; ++chn) {
        float a = A[(((size_t)b * 128 + chn) << 12) + n];
#pragma unroll
        for (int k = 0; k < 32; k++) acc[k] = fmaf(wl[k * 128 + chn], a, acc[k]);
    }
#pragma unroll
    for (int k = 0; k < 32; k++)
        vb[(((size_t)b * 128 + co0 + k) << 12) + n] = f2bf(acc[k] + bl[k]);
}

// ---- PAM rowmax ----
__global__ __launch_bounds__(256) void pam_rowmax(
    const unsigned short* __restrict__ qt, const unsigned short* __restrict__ kt,
    float* __restrict__ rowmax)
{
    const int t  = threadIdx.x;
    const int w  = t >> 6;
    const int L  = t & 63;
    const int ln = L & 31;
    const int g  = L >> 5;
    const int b  = blockIdx.y;
    const int n0 = blockIdx.x << 5;
    __shared__ float red[4][32];

    const f32x16 zero = {0,0,0,0,0,0,0,0,0,0,0,0,0,0,0,0};
    short8 qfrag = *(const short8*)(qt + (((size_t)b * 4096 + n0 + ln) << 4) + (g << 3));

    float mx = -INFINITY;
    for (int mq = (w << 5); mq < 4096; mq += 128) {
        short8 kfrag = *(const short8*)(kt + (((size_t)b * 4096 + mq + ln) << 4) + (g << 3));
        f32x16 s = __builtin_amdgcn_mfma_f32_32x32x16_bf16(kfrag, qfrag, zero, 0, 0, 0);
#pragma unroll
        for (int r = 0; r < 16; r++) mx = fmaxf(mx, s[r]);
    }
    mx = fmaxf(mx, __shfl_xor(mx, 32));
    if (L < 32) red[w][L] = mx;
    __syncthreads();
    if (t < 32) {
        float m = fmaxf(fmaxf(red[0][t], red[1][t]), fmaxf(red[2][t], red[3][t]));
        rowmax[((size_t)b << 12) + n0 + t] = m;
    }
}

// ---- PAM attention, MFMA; out = bf16 (feeds conv2p) -----------------------
__global__ __launch_bounds__(256) void pam_attn_mfma(
    const unsigned short* __restrict__ qt, const unsigned short* __restrict__ kt,
    const unsigned short* __restrict__ vb, const float* __restrict__ rowmax,
    const float* __restrict__ alpha, const float* __restrict__ Y,
    unsigned short* __restrict__ outb)
{
    const int t  = threadIdx.x;
    const int w  = t >> 6;
    const int L  = t & 63;
    const int ln = L & 31;
    const int g  = L >> 5;
    const int b  = blockIdx.y;
    const int n0 = blockIdx.x << 5;
    const int c0 = w << 5;

    __shared__ unsigned short Pf[16 * 256];
    __shared__ float red[4][32];

    const f32x16 zero = {0,0,0,0,0,0,0,0,0,0,0,0,0,0,0,0};
    short8 qfrag = *(const short8*)(qt + (((size_t)b * 4096 + n0 + ln) << 4) + (g << 3));
    const float rm = rowmax[((size_t)b << 12) + n0 + ln];
    const float al = alpha[0];

    f32x16 acc = zero;
    float rs = 0.f;

    for (int m0 = 0; m0 < 4096; m0 += 128) {
        const int mq = m0 + (w << 5);
        short8 kfrag = *(const short8*)(kt + (((size_t)b * 4096 + mq + ln) << 4) + (g << 3));
        f32x16 s = __builtin_amdgcn_mfma_f32_32x32x16_bf16(kfrag, qfrag, zero, 0, 0, 0);

        float p[16];
#pragma unroll
        for (int r = 0; r < 16; r++) { p[r] = __expf(s[r] - rm); rs += p[r]; }
        float xx[16];
#pragma unroll
        for (int r = 0; r < 16; r++) xx[r] = __shfl_xor(p[r], 32);

        unsigned short f0[8], f1[8];
#pragma unroll
        for (int i = 0; i < 4; i++) {
            f0[i]     = f2bf(g ? xx[4 + i]  : p[i]);
            f0[4 + i] = f2bf(g ? p[4 + i]   : xx[i]);
            f1[i]     = f2bf(g ? xx[12 + i] : p[8 + i]);
            f1[4 + i] = f2bf(g ? p[12 + i]  : xx[8 + i]);
        }
        *(short8*)(&Pf[((w << 2) + g) * 256 + (ln << 3)])     = *(short8*)f0;
        *(short8*)(&Pf[((w << 2) + 2 + g) * 256 + (ln << 3)]) = *(short8*)f1;
        __syncthreads();

#pragma unroll
        for (int kk = 0; kk < 8; kk++) {
            short8 pfrag = *(const short8*)(&Pf[((kk << 1) + g) * 256 + (ln << 3)]);
            short8 vfrag = *(const short8*)(vb + (((size_t)b * 128 + c0 + ln) << 12)
                                               + m0 + (kk << 4) + (g << 3));
            acc = __builtin_amdgcn_mfma_f32_32x32x16_bf16(vfrag, pfrag, acc, 0, 0, 0);
        }
        __syncthreads();
    }

    rs += __shfl_xor(rs, 32);
    if (L < 32) red[w][L] = rs;
    __syncthreads();
    const float inv = 1.f / (red[0][ln] + red[1][ln] + red[2][ln] + red[3][ln]);
    const int n = n0 + ln;
#pragma unroll
    for (int r = 0; r < 16; r++) {
        int c = c0 + (r & 3) + ((r >> 2) << 3) + (g << 2);
        size_t idx = (((size_t)b * 128 + c) << 12) + n;
        outb[idx] = f2bf(fmaf(al, acc[r] * inv, Y[idx]));
    }
}

// ---- CAM feat: emits hi/lo bf16 directly (feeds conv2c) -------------------
__global__ __launch_bounds__(256) void cam_feat(
    const float* __restrict__ attn, const float* __restrict__ Bf,
    const float* __restrict__ beta, unsigned short* __restrict__ oh,
    unsigned short* __restrict__ ol)
{
    const int t  = threadIdx.x;
    const int n  = (blockIdx.x << 8) + t;
    const int c0 = blockIdx.y << 5;
    const int b  = blockIdx.z;
    __shared__ float al[32 * 128];
    for (int idx = t; idx < 4096; idx += 256)
        al[idx] = attn[(size_t)b * 16384 + (c0 + (idx >> 7)) * 128 + (idx & 127)];
    __syncthreads();
    float acc[32];
#pragma unroll
    for (int k = 0; k < 32; k++) acc[k] = 0.f;
    for (int d = 0; d < 128; ++d) {
        float v = Bf[(((size_t)b * 128 + d) << 12) + n];
#pragma unroll
        for (int k = 0; k < 32; k++) acc[k] = fmaf(al[k * 128 + d], v, acc[k]);
    }
    float be = beta[0];
#pragma unroll
    for (int k = 0; k < 32; k++) {
        size_t idx = (((size_t)b * 128 + c0 + k) << 12) + n;
        float v = fmaf(be, acc[k], Bf[idx]);
        unsigned short hi = f2bf(v);
        oh[idx] = hi;
        ol[idx] = f2bf(v - bf2f(hi));
    }
}

// ---- Final heads ----
__global__ __launch_bounds__(256) void heads(
    const float* __restrict__ FP, const float* __restrict__ FC,
    const float* __restrict__ Wout, const float* __restrict__ bout,
    const float* __restrict__ Wp3, const float* __restrict__ bp3,
    const float* __restrict__ Wc3, const float* __restrict__ bc3,
    float* __restrict__ out)
{
    const int t = threadIdx.x;
    const int n = (blockIdx.x << 8) + t;
    const int b = blockIdx.y;
    __shared__ float wl[3 * 19 * 128];
    __shared__ float bl[3 * 19];
    for (int idx = t; idx < 2432; idx += 256) {
        wl[idx]        = Wout[idx];
        wl[2432 + idx] = Wp3[idx];
        wl[4864 + idx] = Wc3[idx];
    }
    if (t < 19) { bl[t] = bout[t]; bl[19 + t] = bp3[t]; bl[38 + t] = bc3[t]; }
    __syncthreads();
    float am[19], ap[19], ac[19];
#pragma unroll
    for (int o = 0; o < 19; o++) { am[o] = 0.f; ap[o] = 0.f; ac[o] = 0.f; }
    for (int chn = 0; chn < 128; ++chn) {
        float pv = FP[(((size_t)b * 128 + chn) << 12) + n];
        float cv = FC[(((size_t)b * 128 + chn) << 12) + n];
        float fv = pv + cv;
#pragma unroll
        for (int o = 0; o < 19; o++) {
            am[o] = fmaf(wl[o * 128 + chn], fv, am[o]);
            ap[o] = fmaf(wl[2432 + o * 128 + chn], pv, ap[o]);
            ac[o] = fmaf(wl[4864 + o * 128 + chn], cv, ac[o]);
        }
    }
    const size_t OS = (size_t)8 * 19 * 4096;
#pragma unroll
    for (int o = 0; o < 19; o++) {
        size_t base = (((size_t)b * 19 + o) << 12) + n;
        out[base]          = 1.f / (1.f + __expf(-(am[o] + bl[o])));
        out[OS + base]     = 1.f / (1.f + __expf(-(ap[o] + bl[19 + o])));
        out[2 * OS + base] = 1.f / (1.f + __expf(-(ac[o] + bl[38 + o])));
    }
}

extern "C" void kernel_launch(void* const* d_in, const int* in_sizes, int n_in,
                              void* d_out, int out_size, void* d_ws, size_t ws_size,
                              hipStream_t stream)
{
    const float* x     = (const float*)d_in[0];
    const float* Wp1   = (const float*)d_in[1];
    const float* bnp1  = (const float*)d_in[2];
    const float* Wc1   = (const float*)d_in[3];
    const float* bnc1  = (const float*)d_in[4];
    const float* Wb    = (const float*)d_in[5];
    const float* bb    = (const float*)d_in[6];
    const float* Wc    = (const float*)d_in[7];
    const float* bcv   = (const float*)d_in[8];
    const float* Wd    = (const float*)d_in[9];
    const float* bd    = (const float*)d_in[10];
    const float* alpha = (const float*)d_in[11];
    const float* beta  = (const float*)d_in[12];
    const float* Wp2   = (const float*)d_in[13];
    const float* bnp2  = (const float*)d_in[14];
    const float* Wc2   = (const float*)d_in[15];
    const float* bnc2  = (const float*)d_in[16];
    const float* Wout  = (const float*)d_in[17];
    const float* bo    = (const float*)d_in[18];
    const float* Wp3   = (const float*)d_in[19];
    const float* bp3   = (const float*)d_in[20];
    const float* Wc3   = (const float*)d_in[21];
    const float* bc3   = (const float*)d_in[22];
    float* out = (float*)d_out;

    char* ws = (char*)d_ws;
    const size_t MB = 1u << 20;
    const size_t W1SZ = (size_t)32 * 18432 * 2;
    const size_t W2SZ = (size_t)8 * 18432 * 2;
    float*          bufA     = (float*)(ws);
    float*          bufB     = (float*)(ws + 16 * MB);
    unsigned short* vb       = (unsigned short*)(ws + 32 * MB);  // 8MB
    float*          egy_part = (float*)(ws + 40 * MB);           // 4MB
    float*          bufD     = (float*)(ws + 32 * MB);           // conv2p out (later)
    unsigned short* bh       = (unsigned short*)(ws + 48 * MB);  // 8MB
    unsigned short* blo      = (unsigned short*)(ws + 56 * MB);  // 8MB
    unsigned short* pam_bf   = (unsigned short*)(ws + 48 * MB);  // after Gram
    unsigned short* c2h      = (unsigned short*)(ws + 48 * MB);  // after conv2p
    unsigned short* c2l      = (unsigned short*)(ws + 56 * MB);
    unsigned short* qt       = (unsigned short*)(ws + 64 * MB);
    unsigned short* kt       = (unsigned short*)(ws + 65 * MB);
    float*          rowmax   = (float*)(ws + 66 * MB);
    float*          egy      = (float*)(ws + 66 * MB + (1u << 17));
    unsigned short* wp1      = (unsigned short*)(ws + 67 * MB);
    unsigned short* wc1h     = (unsigned short*)(ws + 67 * MB + W1SZ);
    unsigned short* wc1l     = (unsigned short*)(ws + 67 * MB + 2 * W1SZ);
    unsigned short* wp2      = (unsigned short*)(ws + 67 * MB + 3 * W1SZ);
    unsigned short* wc2h     = (unsigned short*)(ws + 67 * MB + 3 * W1SZ + W2SZ);
    unsigned short* wc2l     = (unsigned short*)(ws + 67 * MB + 3 * W1SZ + 2 * W2SZ);

    dim3 blk(256);
    const int n1 = 32 * 18432;
    const int n2 = 8 * 18432;
    wpack_kernel<<<dim3((n1 + 255) / 256), blk, 0, stream>>>(Wp1, wp1, 512, n1);
    wpack_kernel<<<dim3((n2 + 255) / 256), blk, 0, stream>>>(Wp2, wp2, 128, n2);
    wpack_split_kernel<<<dim3((n1 + 255) / 256), blk, 0, stream>>>(Wc1, wc1h, wc1l, 512, n1);
    wpack_split_kernel<<<dim3((n2 + 255) / 256), blk, 0, stream>>>(Wc2, wc2h, wc2l, 128, n2);

    // fused conv1p + conv1c (shared hi/lo X staging, dbuf, W in regs)
    conv3x3_merged<<<dim3(32, 2, 8), blk, 0, stream>>>(x, wp1, wc1h, wc1l, bnp1, bnc1,
                                                       bufA, bufB, bh, blo);
    // CAM Gram + softmax (consumes bh/bl, egy_part)
    cam_energy_mfma<<<dim3(16, 8, 8), blk, 0, stream>>>(bh, blo, egy_part);
    cam_softmax_fused<<<dim3(8, 8), blk, 0, stream>>>(egy_part, egy);
    // PAM
    pam_qk_1x1<<<dim3(16, 8), blk, 0, stream>>>(bufA, Wb, bb, Wc, bcv, qt, kt);
    pam_v_1x1<<<dim3(16, 4, 8), blk, 0, stream>>>(bufA, Wd, bd, vb);
    pam_rowmax<<<dim3(128, 8), blk, 0, stream>>>(qt, kt, rowmax);
    pam_attn_mfma<<<dim3(128, 8), blk, 0, stream>>>(qt, kt, vb, rowmax, alpha, bufA, pam_bf);
    // conv2p (reads pam_bf, writes bufD over vb/egy_part which are now dead)
    conv3x3_bf<<<dim3(32, 2, 8), blk, 0, stream>>>(pam_bf, 128, wp2, bnp2, bufD);
    // CAM tail (c2h/c2l overwrite pam_bf region after conv2p consumed it)
    cam_feat<<<dim3(16, 4, 8), blk, 0, stream>>>(egy, bufB, beta, c2h, c2l);
    conv3x3_hilo_bf<<<dim3(32, 2, 8), blk, 0, stream>>>(c2h, c2l, 128, wc2h, wc2l, bnc2, bufA);
    // fusion + heads
    heads<<<dim3(16, 8), blk, 0, stream>>>(bufD, bufA, Wout, bo, Wp3, bp3, Wc3, bc3, out);
}

// Round 3
// 769.626 us; speedup vs baseline: 1.2359x; 1.2359x over previous
//
#include <hip/hip_runtime.h>
#include <math.h>

// ---------------------------------------------------------------------------
// DAHead: B=8, Cin=512, Ci=128, H=W=64, N=4096, Ck=16, NC=19.
// R8: break the 2048-wave occupancy cap. Conv wave tile 64px x 32co ->
//     32px x 32co (4096 waves, 4 waves/SIMD). 512-thr 8-wave blocks,
//     __launch_bounds__(512,4) (VGPR<=128; merged needs only 2 accs now).
//     Staging split 2-way (8 ch/thread). W per-lane from global (L2-hot) —
//     now hideable behind 4 waves/SIMD. X dbuf, 1 barrier/chunk.
// ws (byte offsets):
//   bufA@0 (16MB fp32)  bufB@16M (16MB fp32)
//   vb@32M (8MB bf16)   egy_part@40M (4MB fp32)   [both dead before conv2p]
//   bufD@32M (16MB fp32, conv2p out)
//   bh@48M, bl@56M (8MB bf16 each) -> pam_bf@48M -> c2h@48M, c2l@56M
//   qt@64M, kt@65M, rowmax@66M, egy@66M+128K
//   wp1@67M, wc1h, wc1l (1.125MB each), wp2, wc2h, wc2l (288KB each)
// ---------------------------------------------------------------------------

typedef __attribute__((ext_vector_type(8)))  short short8;
typedef __attribute__((ext_vector_type(16))) float f32x16;

__device__ inline unsigned short f2bf(float f) {
    union { float f; unsigned u; } v; v.f = f;
    unsigned r = v.u + 0x7fffu + ((v.u >> 16) & 1u);   // RNE
    return (unsigned short)(r >> 16);
}
__device__ inline float bf2f(unsigned short h) {
    union { unsigned u; float f; } v; v.u = ((unsigned)h) << 16;
    return v.f;
}

// ---- weight prepack: W[co][cin][9] fp32 ->
//      wpack[chunk][tap][g(=ci>>3)][co128][ci8]  (bf16) ----------------------
__global__ __launch_bounds__(256) void wpack_kernel(
    const float* __restrict__ W, unsigned short* __restrict__ wp, int Cin, int total)
{
    int idx = blockIdx.x * 256 + threadIdx.x;
    if (idx >= total) return;
    int chunk = idx / 18432;
    int rem   = idx - chunk * 18432;
    int tap   = rem >> 11;
    int rem2  = rem & 2047;
    int g     = rem2 >> 10;
    int co    = (rem2 >> 3) & 127;
    int ci8   = rem2 & 7;
    int cin   = (chunk << 4) + (g << 3) + ci8;
    wp[idx] = f2bf(W[((size_t)co * Cin + cin) * 9 + tap]);
}

__global__ __launch_bounds__(256) void wpack_split_kernel(
    const float* __restrict__ W, unsigned short* __restrict__ wph,
    unsigned short* __restrict__ wpl, int Cin, int total)
{
    int idx = blockIdx.x * 256 + threadIdx.x;
    if (idx >= total) return;
    int chunk = idx / 18432;
    int rem   = idx - chunk * 18432;
    int tap   = rem >> 11;
    int rem2  = rem & 2047;
    int g     = rem2 >> 10;
    int co    = (rem2 >> 3) & 127;
    int ci8   = rem2 & 7;
    int cin   = (chunk << 4) + (g << 3) + ci8;
    float w = W[((size_t)co * Cin + cin) * 9 + tap];
    unsigned short hi = f2bf(w);
    wph[idx] = hi;
    wpl[idx] = f2bf(w - bf2f(hi));
}

// ---- FUSED conv1: plain (Wp1 -> bufA) + hilo (Wc1 -> bufB,bh,bl) ----------
// 512 thr, 8 waves = (wx row, xh x-half, wy co-half); wave tile 32px x 32co.
// grid (32, 2, 8). LDS 33792 B. VGPR-capped via __launch_bounds__(512,4).
__global__ __launch_bounds__(512, 4) void conv3x3_merged(
    const float* __restrict__ xin,
    const unsigned short* __restrict__ wpp,
    const unsigned short* __restrict__ wph, const unsigned short* __restrict__ wpl,
    const float* __restrict__ bnp, const float* __restrict__ bnc,
    float* __restrict__ outP, float* __restrict__ outC,
    unsigned short* __restrict__ outh, unsigned short* __restrict__ outl)
{
    const int t   = threadIdx.x;
    const int w   = t >> 6;           // 0..7
    const int wx  = w & 1;            // output row
    const int xh  = (w >> 1) & 1;     // x half (0..31 / 32..63)
    const int wy  = w >> 2;           // co 32-half within block's 64
    const int ln  = t & 63;
    const int l31 = ln & 31;
    const int g   = ln >> 5;
    const int y0  = blockIdx.x << 1;
    const int co0 = blockIdx.y << 6;
    const int b   = blockIdx.z;

    // staging: 2 threads per position (8 channels each); halos stay zero
    const int pos  = t >> 1;          // 0..255 interior position
    const int cg   = t & 1;           // channel group
    const int sr   = pos >> 6;        // row 0..3  (gy = y0-1+sr)
    const int sx   = pos & 63;        // gx
    const int sgy  = y0 - 1 + sr;
    const bool sv  = (unsigned)sgy < 64u;
    const int spid = sr * 66 + sx + 1;
    const int soff = (cg ? 2112 : 0) + (spid << 3);

    __shared__ __align__(16) unsigned short Xh[2][4224];   // [buf][g*2112 + pid*8]
    __shared__ __align__(16) unsigned short Xo[2][4224];   // 33792 B total

    for (int i = t; i < 1056; i += 512) {
        uint4 z; z.x = 0; z.y = 0; z.z = 0; z.w = 0;
        ((uint4*)Xh)[i] = z;
        ((uint4*)Xo)[i] = z;
    }

    const int co = co0 + (wy << 5) + l31;
    const unsigned short* wPb = wpp + (size_t)(g << 10) + ((size_t)co << 3);
    const unsigned short* wHb = wph + (size_t)(g << 10) + ((size_t)co << 3);
    const unsigned short* wLb = wpl + (size_t)(g << 10) + ((size_t)co << 3);
    const float* xsrc = xin + (((size_t)b * 512 + (cg << 3)) << 12) + (sgy << 6) + sx;

    const f32x16 zero = {0,0,0,0,0,0,0,0,0,0,0,0,0,0,0,0};
    f32x16 ap = zero, ac = zero;

    float xv[8];
    if (sv) {
#pragma unroll
        for (int c = 0; c < 8; c++) xv[c] = xsrc[(size_t)c << 12];
    }
    __syncthreads();   // zero-init done

    if (sv) {
        unsigned short th[8], tl[8];
#pragma unroll
        for (int c = 0; c < 8; c++) {
            unsigned short hi = f2bf(xv[c]);
            th[c] = hi; tl[c] = f2bf(xv[c] - bf2f(hi));
        }
        *(uint4*)&Xh[0][soff] = *(uint4*)th;
        *(uint4*)&Xo[0][soff] = *(uint4*)tl;
    }

    int cur = 0;
    for (int ch = 0; ch < 32; ++ch) {
        __syncthreads();
        const bool pf = (ch < 31);
        if (pf && sv) {
#pragma unroll
            for (int c = 0; c < 8; c++)
                xv[c] = xsrc[((size_t)(ch + 1) << 16) + ((size_t)c << 12)];
        }
        const size_t wo = (size_t)ch * 18432;
#pragma unroll 3
        for (int tap = 0; tap < 9; ++tap) {
            const int dy = tap / 3, dx = tap - dy * 3;
            const int row = wx + dy;
            const int xi = (g ? 2112 : 0) + (((row * 66) + (xh << 5) + l31 + dx) << 3);
            short8 vap = *(const short8*)(wPb + wo + tap * 2048);
            short8 vah = *(const short8*)(wHb + wo + tap * 2048);
            short8 val = *(const short8*)(wLb + wo + tap * 2048);
            short8 bh_ = *(const short8*)&Xh[cur][xi];
            short8 bl_ = *(const short8*)&Xo[cur][xi];
            ap = __builtin_amdgcn_mfma_f32_32x32x16_bf16(vap, bh_, ap, 0, 0, 0);
            ac = __builtin_amdgcn_mfma_f32_32x32x16_bf16(vah, bh_, ac, 0, 0, 0);
            ac = __builtin_amdgcn_mfma_f32_32x32x16_bf16(vah, bl_, ac, 0, 0, 0);
            ac = __builtin_amdgcn_mfma_f32_32x32x16_bf16(val, bh_, ac, 0, 0, 0);
        }
        if (pf && sv) {
            unsigned short th[8], tl[8];
#pragma unroll
            for (int c = 0; c < 8; c++) {
                unsigned short hi = f2bf(xv[c]);
                th[c] = hi; tl[c] = f2bf(xv[c] - bf2f(hi));
            }
            const int nb = cur ^ 1;
            *(uint4*)&Xh[nb][soff] = *(uint4*)th;
            *(uint4*)&Xo[nb][soff] = *(uint4*)tl;
        }
        cur ^= 1;
    }

    const int y = y0 + wx;
    const int x = (xh << 5) + l31;
#pragma unroll
    for (int r = 0; r < 16; r++) {
        int c2 = co0 + (wy << 5) + (r & 3) + ((r >> 2) << 3) + (g << 2);
        size_t o = (((size_t)b * 128 + c2) << 12) + (y << 6) + x;
        float vp = fmaf(ap[r], bnp[c2], bnp[128 + c2]);
        vp = vp > 0.f ? vp : 0.f;
        outP[o] = vp;
        float vc = fmaf(ac[r], bnc[c2], bnc[128 + c2]);
        vc = vc > 0.f ? vc : 0.f;
        outC[o] = vc;
        unsigned short hi = f2bf(vc);
        outh[o] = hi;
        outl[o] = f2bf(vc - bf2f(hi));
    }
}

// ---- plain 3x3 conv, bf16 input (conv2p). 512 thr, 8 waves. ---------------
__global__ __launch_bounds__(512, 4) void conv3x3_bf(
    const unsigned short* __restrict__ xin, int Cin,
    const unsigned short* __restrict__ wpk, const float* __restrict__ bn,
    float* __restrict__ out_f32)
{
    const int t   = threadIdx.x;
    const int w   = t >> 6;
    const int wx  = w & 1;
    const int xh  = (w >> 1) & 1;
    const int wy  = w >> 2;
    const int ln  = t & 63;
    const int l31 = ln & 31;
    const int g   = ln >> 5;
    const int y0  = blockIdx.x << 1;
    const int co0 = blockIdx.y << 6;
    const int b   = blockIdx.z;

    const int pos  = t >> 1;
    const int cg   = t & 1;
    const int sr   = pos >> 6;
    const int sx   = pos & 63;
    const int sgy  = y0 - 1 + sr;
    const bool sv  = (unsigned)sgy < 64u;
    const int soff = (cg ? 2112 : 0) + ((sr * 66 + sx + 1) << 3);

    __shared__ __align__(16) unsigned short Xl[2][4224];   // 16896 B

    for (int i = t; i < 1056; i += 512) {
        uint4 z; z.x = 0; z.y = 0; z.z = 0; z.w = 0;
        ((uint4*)Xl)[i] = z;
    }

    const int co = co0 + (wy << 5) + l31;
    const unsigned short* wB = wpk + (size_t)(g << 10) + ((size_t)co << 3);
    const unsigned short* xsrc = xin + (((size_t)b * Cin + (cg << 3)) << 12) + (sgy << 6) + sx;

    const f32x16 zero = {0,0,0,0,0,0,0,0,0,0,0,0,0,0,0,0};
    f32x16 acc = zero;

    unsigned short xv[8];
    if (sv) {
#pragma unroll
        for (int c = 0; c < 8; c++) xv[c] = xsrc[(size_t)c << 12];
    }
    __syncthreads();

    if (sv) *(uint4*)&Xl[0][soff] = *(uint4*)xv;

    const int nchunks = Cin >> 4;
    int cur = 0;
    for (int ch = 0; ch < nchunks; ++ch) {
        __syncthreads();
        const bool pf = (ch < nchunks - 1);
        if (pf && sv) {
#pragma unroll
            for (int c = 0; c < 8; c++)
                xv[c] = xsrc[((size_t)(ch + 1) << 16) + ((size_t)c << 12)];
        }
        const size_t wo = (size_t)ch * 18432;
#pragma unroll 3
        for (int tap = 0; tap < 9; ++tap) {
            const int dy = tap / 3, dx = tap - dy * 3;
            const int row = wx + dy;
            const int xi = (g ? 2112 : 0) + (((row * 66) + (xh << 5) + l31 + dx) << 3);
            short8 a  = *(const short8*)(wB + wo + tap * 2048);
            short8 b0 = *(const short8*)&Xl[cur][xi];
            acc = __builtin_amdgcn_mfma_f32_32x32x16_bf16(a, b0, acc, 0, 0, 0);
        }
        if (pf && sv) *(uint4*)&Xl[cur ^ 1][soff] = *(uint4*)xv;
        cur ^= 1;
    }

    const int y = y0 + wx;
    const int x = (xh << 5) + l31;
#pragma unroll
    for (int r = 0; r < 16; r++) {
        int c2 = co0 + (wy << 5) + (r & 3) + ((r >> 2) << 3) + (g << 2);
        float v = fmaf(acc[r], bn[c2], bn[128 + c2]);
        v = v > 0.f ? v : 0.f;
        out_f32[(((size_t)b * 128 + c2) << 12) + (y << 6) + x] = v;
    }
}

// ---- hilo 3x3 conv, pre-split bf16 inputs (conv2c). 512 thr, 8 waves. -----
__global__ __launch_bounds__(512, 4) void conv3x3_hilo_bf(
    const unsigned short* __restrict__ xhg, const unsigned short* __restrict__ xlg,
    int Cin, const unsigned short* __restrict__ wph, const unsigned short* __restrict__ wpl,
    const float* __restrict__ bn, float* __restrict__ out_f32)
{
    const int t   = threadIdx.x;
    const int w   = t >> 6;
    const int wx  = w & 1;
    const int xh  = (w >> 1) & 1;
    const int wy  = w >> 2;
    const int ln  = t & 63;
    const int l31 = ln & 31;
    const int g   = ln >> 5;
    const int y0  = blockIdx.x << 1;
    const int co0 = blockIdx.y << 6;
    const int b   = blockIdx.z;

    const int pos  = t >> 1;
    const int cg   = t & 1;
    const int sr   = pos >> 6;
    const int sx   = pos & 63;
    const int sgy  = y0 - 1 + sr;
    const bool sv  = (unsigned)sgy < 64u;
    const int soff = (cg ? 2112 : 0) + ((sr * 66 + sx + 1) << 3);

    __shared__ __align__(16) unsigned short Xh[2][4224];
    __shared__ __align__(16) unsigned short Xo[2][4224];   // 33792 B

    for (int i = t; i < 1056; i += 512) {
        uint4 z; z.x = 0; z.y = 0; z.z = 0; z.w = 0;
        ((uint4*)Xh)[i] = z;
        ((uint4*)Xo)[i] = z;
    }

    const int co = co0 + (wy << 5) + l31;
    const unsigned short* wHb = wph + (size_t)(g << 10) + ((size_t)co << 3);
    const unsigned short* wLb = wpl + (size_t)(g << 10) + ((size_t)co << 3);
    const unsigned short* hsrc = xhg + (((size_t)b * Cin + (cg << 3)) << 12) + (sgy << 6) + sx;
    const unsigned short* lsrc = xlg + (((size_t)b * Cin + (cg << 3)) << 12) + (sgy << 6) + sx;

    const f32x16 zero = {0,0,0,0,0,0,0,0,0,0,0,0,0,0,0,0};
    f32x16 acc = zero;

    unsigned short hv[8], lv[8];
    if (sv) {
#pragma unroll
        for (int c = 0; c < 8; c++) { hv[c] = hsrc[(size_t)c << 12]; lv[c] = lsrc[(size_t)c << 12]; }
    }
    __syncthreads();

    if (sv) {
        *(uint4*)&Xh[0][soff] = *(uint4*)hv;
        *(uint4*)&Xo[0][soff] = *(uint4*)lv;
    }

    const int nchunks = Cin >> 4;
    int cur = 0;
    for (int ch = 0; ch < nchunks; ++ch) {
        __syncthreads();
        const bool pf = (ch < nchunks - 1);
        if (pf && sv) {
#pragma unroll
            for (int c = 0; c < 8; c++) {
                hv[c] = hsrc[((size_t)(ch + 1) << 16) + ((size_t)c << 12)];
                lv[c] = lsrc[((size_t)(ch + 1) << 16) + ((size_t)c << 12)];
            }
        }
        const size_t wo = (size_t)ch * 18432;
#pragma unroll 3
        for (int tap = 0; tap < 9; ++tap) {
            const int dy = tap / 3, dx = tap - dy * 3;
            const int row = wx + dy;
            const int xi = (g ? 2112 : 0) + (((row * 66) + (xh << 5) + l31 + dx) << 3);
            short8 ah  = *(const short8*)(wHb + wo + tap * 2048);
            short8 al  = *(const short8*)(wLb + wo + tap * 2048);
            short8 bh_ = *(const short8*)&Xh[cur][xi];
            short8 bl_ = *(const short8*)&Xo[cur][xi];
            acc = __builtin_amdgcn_mfma_f32_32x32x16_bf16(ah, bh_, acc, 0, 0, 0);
            acc = __builtin_amdgcn_mfma_f32_32x32x16_bf16(ah, bl_, acc, 0, 0, 0);
            acc = __builtin_amdgcn_mfma_f32_32x32x16_bf16(al, bh_, acc, 0, 0, 0);
        }
        if (pf && sv) {
            const int nb = cur ^ 1;
            *(uint4*)&Xh[nb][soff] = *(uint4*)hv;
            *(uint4*)&Xo[nb][soff] = *(uint4*)lv;
        }
        cur ^= 1;
    }

    const int y = y0 + wx;
    const int x = (xh << 5) + l31;
#pragma unroll
    for (int r = 0; r < 16; r++) {
        int c2 = co0 + (wy << 5) + (r & 3) + ((r >> 2) << 3) + (g << 2);
        float v = fmaf(acc[r], bn[c2], bn[128 + c2]);
        v = v > 0.f ? v : 0.f;
        out_f32[(((size_t)b * 128 + c2) << 12) + (y << 6) + x] = v;
    }
}

// ---- CAM Gram via hi/lo MFMA, n-split partials. grid (16, 8, 8) -----------
__global__ __launch_bounds__(256) void cam_energy_mfma(
    const unsigned short* __restrict__ bh, const unsigned short* __restrict__ bl,
    float* __restrict__ egy_part)
{
    const int t   = threadIdx.x;
    const int w   = t >> 6;
    const int ln  = t & 63;
    const int l31 = ln & 31;
    const int g   = ln >> 5;
    const int i0  = (blockIdx.x >> 2) << 5;
    const int j0  = (blockIdx.x & 3) << 5;
    const int nseg = blockIdx.y;
    const int b   = blockIdx.z;

    __shared__ float red[4][64][17];

    const f32x16 zero = {0,0,0,0,0,0,0,0,0,0,0,0,0,0,0,0};
    f32x16 acc = zero;
    const int nb = (nseg << 9) + (w << 7) + (g << 3);
    const size_t ri = ((size_t)b * 128 + i0 + l31) << 12;
    const size_t rj = ((size_t)b * 128 + j0 + l31) << 12;

#pragma unroll
    for (int c = 0; c < 8; c++) {
        const int n0 = nb + (c << 4);
        short8 ah  = *(const short8*)(bh + ri + n0);
        short8 al  = *(const short8*)(bl + ri + n0);
        short8 bhf = *(const short8*)(bh + rj + n0);
        short8 blf = *(const short8*)(bl + rj + n0);
        acc = __builtin_amdgcn_mfma_f32_32x32x16_bf16(ah, bhf, acc, 0, 0, 0);
        acc = __builtin_amdgcn_mfma_f32_32x32x16_bf16(ah, blf, acc, 0, 0, 0);
        acc = __builtin_amdgcn_mfma_f32_32x32x16_bf16(al, bhf, acc, 0, 0, 0);
    }
#pragma unroll
    for (int r = 0; r < 16; r++) red[w][ln][r] = acc[r];
    __syncthreads();

    const int lane = t & 63;
    const int rq   = t >> 6;
    float* base = egy_part + (((size_t)(nseg * 8 + b)) << 14);
#pragma unroll
    for (int e = 0; e < 4; e++) {
        const int reg = (rq << 2) + e;
        float v = red[0][lane][reg] + red[1][lane][reg]
                + red[2][lane][reg] + red[3][lane][reg];
        const int i = i0 + (reg & 3) + ((reg >> 2) << 3) + ((lane >> 5) << 2);
        base[i * 128 + j0 + (lane & 31)] = v;
    }
}

// ---- CAM softmax of (rowmax - e), fused 8-seg reduce. grid (8, 8) ---------
__global__ __launch_bounds__(256) void cam_softmax_fused(
    const float* __restrict__ egy_part, float* __restrict__ egy)
{
    const int b   = blockIdx.x;
    const int rg  = blockIdx.y;
    const int t   = threadIdx.x;
    const int row = (rg << 4) + (t >> 4);
    const int jg  = t & 15;

    float e[8];
#pragma unroll
    for (int jj = 0; jj < 8; jj++) e[jj] = 0.f;
    for (int seg = 0; seg < 8; seg++) {
        const float* p = egy_part + (((size_t)(seg * 8 + b)) << 14) + row * 128 + (jg << 3);
#pragma unroll
        for (int jj = 0; jj < 8; jj++) e[jj] += p[jj];
    }
    float mn = e[0];
#pragma unroll
    for (int jj = 1; jj < 8; jj++) mn = fminf(mn, e[jj]);
#pragma unroll
    for (int k = 1; k < 16; k <<= 1) mn = fminf(mn, __shfl_xor(mn, k));
    float s = 0.f;
#pragma unroll
    for (int jj = 0; jj < 8; jj++) { float p = __expf(mn - e[jj]); e[jj] = p; s += p; }
#pragma unroll
    for (int k = 1; k < 16; k <<= 1) s += __shfl_xor(s, k);
    const float inv = 1.f / s;
    float* orow = egy + ((size_t)b << 14) + row * 128 + (jg << 3);
#pragma unroll
    for (int jj = 0; jj < 8; jj++) orow[jj] = e[jj] * inv;
}

// ---- PAM Q/K producer ----
__global__ __launch_bounds__(256) void pam_qk_1x1(
    const float* __restrict__ A, const float* __restrict__ Wb, const float* __restrict__ bb,
    const float* __restrict__ Wc, const float* __restrict__ bc,
    unsigned short* __restrict__ qt, unsigned short* __restrict__ kt)
{
    __shared__ float wl[2 * 16 * 128];
    __shared__ float bl[32];
    const int t = threadIdx.x;
    const int n = (blockIdx.x << 8) + t;
    const int b = blockIdx.y;
    for (int idx = t; idx < 2048; idx += 256) { wl[idx] = Wb[idx]; wl[2048 + idx] = Wc[idx]; }
    if (t < 16) { bl[t] = bb[t]; bl[16 + t] = bc[t]; }
    __syncthreads();
    float ab[16], ac[16];
#pragma unroll
    for (int k = 0; k < 16; k++) { ab[k] = 0.f; ac[k] = 0.f; }
    for (int chn = 0; chn < 128; ++chn) {
        float a = A[(((size_t)b * 128 + chn) << 12) + n];
#pragma unroll
        for (int k = 0; k < 16; k++) {
            ab[k] = fmaf(wl[k * 128 + chn], a, ab[k]);
            ac[k] = fmaf(wl[2048 + k * 128 + chn], a, ac[k]);
        }
    }
    unsigned short uq[16], uk[16];
#pragma unroll
    for (int k = 0; k < 16; k++) {
        uq[k] = f2bf(ab[k] + bl[k]);
        uk[k] = f2bf(ac[k] + bl[16 + k]);
    }
    size_t row = (size_t)b * 4096 + n;
    ((uint4*)qt)[row * 2 + 0] = ((uint4*)uq)[0];
    ((uint4*)qt)[row * 2 + 1] = ((uint4*)uq)[1];
    ((uint4*)kt)[row * 2 + 0] = ((uint4*)uk)[0];
    ((uint4*)kt)[row * 2 + 1] = ((uint4*)uk)[1];
}

// ---- PAM V producer ----
__global__ __launch_bounds__(256) void pam_v_1x1(
    const float* __restrict__ A, const float* __restrict__ Wd, const float* __restrict__ bd,
    unsigned short* __restrict__ vb)
{
    __shared__ float wl[32 * 128];
    __shared__ float bl[32];
    const int t   = threadIdx.x;
    const int n   = (blockIdx.x << 8) + t;
    const int co0 = blockIdx.y << 5;
    const int b   = blockIdx.z;
    for (int idx = t; idx < 4096; idx += 256) {
        int c2 = idx >> 7, chv = idx & 127;
        wl[idx] = Wd[(co0 + c2) * 128 + chv];
    }
    if (t < 32) bl[t] = bd[co0 + t];
    __syncthreads();
    float acc[32];
#pragma unroll
    for (int k = 0; k < 32; k++) acc[k] = 0.f;
    for (int chn = 0; chn < 128; ++chn) {
        float a = A[(((size_t)b * 128 + chn) << 12) + n];
#pragma unroll
        for (int k = 0; k < 32; k++) acc[k] = fmaf(wl[k * 128 + chn], a, acc[k]);
    }
#pragma unroll
    for (int k = 0; k < 32; k++)
        vb[(((size_t)b * 128 + co0 + k) << 12) + n] = f2bf(acc[k] + bl[k]);
}

// ---- PAM rowmax ----
__global__ __launch_bounds__(256) void pam_rowmax(
    const unsigned short* __restrict__ qt, const unsigned short* __restrict__ kt,
    float* __restrict__ rowmax)
{
    const int t  = threadIdx.x;
    const int w  = t >> 6;
    const int L  = t & 63;
    const int ln = L & 31;
    const int g  = L >> 5;
    const int b  = blockIdx.y;
    const int n0 = blockIdx.x << 5;
    __shared__ float red[4][32];

    const f32x16 zero = {0,0,0,0,0,0,0,0,0,0,0,0,0,0,0,0};
    short8 qfrag = *(const short8*)(qt + (((size_t)b * 4096 + n0 + ln) << 4) + (g << 3));

    float mx = -INFINITY;
    for (int mq = (w << 5); mq < 4096; mq += 128) {
        short8 kfrag = *(const short8*)(kt + (((size_t)b * 4096 + mq + ln) << 4) + (g << 3));
        f32x16 s = __builtin_amdgcn_mfma_f32_32x32x16_bf16(kfrag, qfrag, zero, 0, 0, 0);
#pragma unroll
        for (int r = 0; r < 16; r++) mx = fmaxf(mx, s[r]);
    }
    mx = fmaxf(mx, __shfl_xor(mx, 32));
    if (L < 32) red[w][L] = mx;
    __syncthreads();
    if (t < 32) {
        float m = fmaxf(fmaxf(red[0][t], red[1][t]), fmaxf(red[2][t], red[3][t]));
        rowmax[((size_t)b << 12) + n0 + t] = m;
    }
}

// ---- PAM attention, MFMA; out = bf16 (feeds conv2p) -----------------------
__global__ __launch_bounds__(256) void pam_attn_mfma(
    const unsigned short* __restrict__ qt, const unsigned short* __restrict__ kt,
    const unsigned short* __restrict__ vb, const float* __restrict__ rowmax,
    const float* __restrict__ alpha, const float* __restrict__ Y,
    unsigned short* __restrict__ outb)
{
    const int t  = threadIdx.x;
    const int w  = t >> 6;
    const int L  = t & 63;
    const int ln = L & 31;
    const int g  = L >> 5;
    const int b  = blockIdx.y;
    const int n0 = blockIdx.x << 5;
    const int c0 = w << 5;

    __shared__ unsigned short Pf[16 * 256];
    __shared__ float red[4][32];

    const f32x16 zero = {0,0,0,0,0,0,0,0,0,0,0,0,0,0,0,0};
    short8 qfrag = *(const short8*)(qt + (((size_t)b * 4096 + n0 + ln) << 4) + (g << 3));
    const float rm = rowmax[((size_t)b << 12) + n0 + ln];
    const float al = alpha[0];

    f32x16 acc = zero;
    float rs = 0.f;

    for (int m0 = 0; m0 < 4096; m0 += 128) {
        const int mq = m0 + (w << 5);
        short8 kfrag = *(const short8*)(kt + (((size_t)b * 4096 + mq + ln) << 4) + (g << 3));
        f32x16 s = __builtin_amdgcn_mfma_f32_32x32x16_bf16(kfrag, qfrag, zero, 0, 0, 0);

        float p[16];
#pragma unroll
        for (int r = 0; r < 16; r++) { p[r] = __expf(s[r] - rm); rs += p[r]; }
        float xx[16];
#pragma unroll
        for (int r = 0; r < 16; r++) xx[r] = __shfl_xor(p[r], 32);

        unsigned short f0[8], f1[8];
#pragma unroll
        for (int i = 0; i < 4; i++) {
            f0[i]     = f2bf(g ? xx[4 + i]  : p[i]);
            f0[4 + i] = f2bf(g ? p[4 + i]   : xx[i]);
            f1[i]     = f2bf(g ? xx[12 + i] : p[8 + i]);
            f1[4 + i] = f2bf(g ? p[12 + i]  : xx[8 + i]);
        }
        *(short8*)(&Pf[((w << 2) + g) * 256 + (ln << 3)])     = *(short8*)f0;
        *(short8*)(&Pf[((w << 2) + 2 + g) * 256 + (ln << 3)]) = *(short8*)f1;
        __syncthreads();

#pragma unroll
        for (int kk = 0; kk < 8; kk++) {
            short8 pfrag = *(const short8*)(&Pf[((kk << 1) + g) * 256 + (ln << 3)]);
            short8 vfrag = *(const short8*)(vb + (((size_t)b * 128 + c0 + ln) << 12)
                                               + m0 + (kk << 4) + (g << 3));
            acc = __builtin_amdgcn_mfma_f32_32x32x16_bf16(vfrag, pfrag, acc, 0, 0, 0);
        }
        __syncthreads();
    }

    rs += __shfl_xor(rs, 32);
    if (L < 32) red[w][L] = rs;
    __syncthreads();
    const float inv = 1.f / (red[0][ln] + red[1][ln] + red[2][ln] + red[3][ln]);
    const int n = n0 + ln;
#pragma unroll
    for (int r = 0; r < 16; r++) {
        int c = c0 + (r & 3) + ((r >> 2) << 3) + (g << 2);
        size_t idx = (((size_t)b * 128 + c) << 12) + n;
        outb[idx] = f2bf(fmaf(al, acc[r] * inv, Y[idx]));
    }
}

// ---- CAM feat: emits hi/lo bf16 directly (feeds conv2c) -------------------
__global__ __launch_bounds__(256) void cam_feat(
    const float* __restrict__ attn, const float* __restrict__ Bf,
    const float* __restrict__ beta, unsigned short* __restrict__ oh,
    unsigned short* __restrict__ ol)
{
    const int t  = threadIdx.x;
    const int n  = (blockIdx.x << 8) + t;
    const int c0 = blockIdx.y << 5;
    const int b  = blockIdx.z;
    __shared__ float al[32 * 128];
    for (int idx = t; idx < 4096; idx += 256)
        al[idx] = attn[(size_t)b * 16384 + (c0 + (idx >> 7)) * 128 + (idx & 127)];
    __syncthreads();
    float acc[32];
#pragma unroll
    for (int k = 0; k < 32; k++) acc[k] = 0.f;
    for (int d = 0; d < 128; ++d) {
        float v = Bf[(((size_t)b * 128 + d) << 12) + n];
#pragma unroll
        for (int k = 0; k < 32; k++) acc[k] = fmaf(al[k * 128 + d], v, acc[k]);
    }
    float be = beta[0];
#pragma unroll
    for (int k = 0; k < 32; k++) {
        size_t idx = (((size_t)b * 128 + c0 + k) << 12) + n;
        float v = fmaf(be, acc[k], Bf[idx]);
        unsigned short hi = f2bf(v);
        oh[idx] = hi;
        ol[idx] = f2bf(v - bf2f(hi));
    }
}

// ---- Final heads ----
__global__ __launch_bounds__(256) void heads(
    const float* __restrict__ FP, const float* __restrict__ FC,
    const float* __restrict__ Wout, const float* __restrict__ bout,
    const float* __restrict__ Wp3, const float* __restrict__ bp3,
    const float* __restrict__ Wc3, const float* __restrict__ bc3,
    float* __restrict__ out)
{
    const int t = threadIdx.x;
    const int n = (blockIdx.x << 8) + t;
    const int b = blockIdx.y;
    __shared__ float wl[3 * 19 * 128];
    __shared__ float bl[3 * 19];
    for (int idx = t; idx < 2432; idx += 256) {
        wl[idx]        = Wout[idx];
        wl[2432 + idx] = Wp3[idx];
        wl[4864 + idx] = Wc3[idx];
    }
    if (t < 19) { bl[t] = bout[t]; bl[19 + t] = bp3[t]; bl[38 + t] = bc3[t]; }
    __syncthreads();
    float am[19], ap[19], ac[19];
#pragma unroll
    for (int o = 0; o < 19; o++) { am[o] = 0.f; ap[o] = 0.f; ac[o] = 0.f; }
    for (int chn = 0; chn < 128; ++chn) {
        float pv = FP[(((size_t)b * 128 + chn) << 12) + n];
        float cv = FC[(((size_t)b * 128 + chn) << 12) + n];
        float fv = pv + cv;
#pragma unroll
        for (int o = 0; o < 19; o++) {
            am[o] = fmaf(wl[o * 128 + chn], fv, am[o]);
            ap[o] = fmaf(wl[2432 + o * 128 + chn], pv, ap[o]);
            ac[o] = fmaf(wl[4864 + o * 128 + chn], cv, ac[o]);
        }
    }
    const size_t OS = (size_t)8 * 19 * 4096;
#pragma unroll
    for (int o = 0; o < 19; o++) {
        size_t base = (((size_t)b * 19 + o) << 12) + n;
        out[base]          = 1.f / (1.f + __expf(-(am[o] + bl[o])));
        out[OS + base]     = 1.f / (1.f + __expf(-(ap[o] + bl[19 + o])));
        out[2 * OS + base] = 1.f / (1.f + __expf(-(ac[o] + bl[38 + o])));
    }
}

extern "C" void kernel_launch(void* const* d_in, const int* in_sizes, int n_in,
                              void* d_out, int out_size, void* d_ws, size_t ws_size,
                              hipStream_t stream)
{
    const float* x     = (const float*)d_in[0];
    const float* Wp1   = (const float*)d_in[1];
    const float* bnp1  = (const float*)d_in[2];
    const float* Wc1   = (const float*)d_in[3];
    const float* bnc1  = (const float*)d_in[4];
    const float* Wb    = (const float*)d_in[5];
    const float* bb    = (const float*)d_in[6];
    const float* Wc    = (const float*)d_in[7];
    const float* bcv   = (const float*)d_in[8];
    const float* Wd    = (const float*)d_in[9];
    const float* bd    = (const float*)d_in[10];
    const float* alpha = (const float*)d_in[11];
    const float* beta  = (const float*)d_in[12];
    const float* Wp2   = (const float*)d_in[13];
    const float* bnp2  = (const float*)d_in[14];
    const float* Wc2   = (const float*)d_in[15];
    const float* bnc2  = (const float*)d_in[16];
    const float* Wout  = (const float*)d_in[17];
    const float* bo    = (const float*)d_in[18];
    const float* Wp3   = (const float*)d_in[19];
    const float* bp3   = (const float*)d_in[20];
    const float* Wc3   = (const float*)d_in[21];
    const float* bc3   = (const float*)d_in[22];
    float* out = (float*)d_out;

    char* ws = (char*)d_ws;
    const size_t MB = 1u << 20;
    const size_t W1SZ = (size_t)32 * 18432 * 2;
    const size_t W2SZ = (size_t)8 * 18432 * 2;
    float*          bufA     = (float*)(ws);
    float*          bufB     = (float*)(ws + 16 * MB);
    unsigned short* vb       = (unsigned short*)(ws + 32 * MB);  // 8MB
    float*          egy_part = (float*)(ws + 40 * MB);           // 4MB
    float*          bufD     = (float*)(ws + 32 * MB);           // conv2p out (later)
    unsigned short* bh       = (unsigned short*)(ws + 48 * MB);  // 8MB
    unsigned short* blo      = (unsigned short*)(ws + 56 * MB);  // 8MB
    unsigned short* pam_bf   = (unsigned short*)(ws + 48 * MB);  // after Gram
    unsigned short* c2h      = (unsigned short*)(ws + 48 * MB);  // after conv2p
    unsigned short* c2l      = (unsigned short*)(ws + 56 * MB);
    unsigned short* qt       = (unsigned short*)(ws + 64 * MB);
    unsigned short* kt       = (unsigned short*)(ws + 65 * MB);
    float*          rowmax   = (float*)(ws + 66 * MB);
    float*          egy      = (float*)(ws + 66 * MB + (1u << 17));
    unsigned short* wp1      = (unsigned short*)(ws + 67 * MB);
    unsigned short* wc1h     = (unsigned short*)(ws + 67 * MB + W1SZ);
    unsigned short* wc1l     = (unsigned short*)(ws + 67 * MB + 2 * W1SZ);
    unsigned short* wp2      = (unsigned short*)(ws + 67 * MB + 3 * W1SZ);
    unsigned short* wc2h     = (unsigned short*)(ws + 67 * MB + 3 * W1SZ + W2SZ);
    unsigned short* wc2l     = (unsigned short*)(ws + 67 * MB + 3 * W1SZ + 2 * W2SZ);

    dim3 blk(256);
    dim3 blk512(512);
    const int n1 = 32 * 18432;
    const int n2 = 8 * 18432;
    wpack_kernel<<<dim3((n1 + 255) / 256), blk, 0, stream>>>(Wp1, wp1, 512, n1);
    wpack_kernel<<<dim3((n2 + 255) / 256), blk, 0, stream>>>(Wp2, wp2, 128, n2);
    wpack_split_kernel<<<dim3((n1 + 255) / 256), blk, 0, stream>>>(Wc1, wc1h, wc1l, 512, n1);
    wpack_split_kernel<<<dim3((n2 + 255) / 256), blk, 0, stream>>>(Wc2, wc2h, wc2l, 128, n2);

    // fused conv1p + conv1c (shared hi/lo X staging, dbuf, W in regs, 8 waves)
    conv3x3_merged<<<dim3(32, 2, 8), blk512, 0, stream>>>(x, wp1, wc1h, wc1l, bnp1, bnc1,
                                                          bufA, bufB, bh, blo);
    // CAM Gram + softmax (consumes bh/bl, egy_part)
    cam_energy_mfma<<<dim3(16, 8, 8), blk, 0, stream>>>(bh, blo, egy_part);
    cam_softmax_fused<<<dim3(8, 8), blk, 0, stream>>>(egy_part, egy);
    // PAM
    pam_qk_1x1<<<dim3(16, 8), blk, 0, stream>>>(bufA, Wb, bb, Wc, bcv, qt, kt);
    pam_v_1x1<<<dim3(16, 4, 8), blk, 0, stream>>>(bufA, Wd, bd, vb);
    pam_rowmax<<<dim3(128, 8), blk, 0, stream>>>(qt, kt, rowmax);
    pam_attn_mfma<<<dim3(128, 8), blk, 0, stream>>>(qt, kt, vb, rowmax, alpha, bufA, pam_bf);
    // conv2p (reads pam_bf, writes bufD over vb/egy_part which are now dead)
    conv3x3_bf<<<dim3(32, 2, 8), blk512, 0, stream>>>(pam_bf, 128, wp2, bnp2, bufD);
    // CAM tail (c2h/c2l overwrite pam_bf region after conv2p consumed it)
    cam_feat<<<dim3(16, 4, 8), blk, 0, stream>>>(egy, bufB, beta, c2h, c2l);
    conv3x3_hilo_bf<<<dim3(32, 2, 8), blk512, 0, stream>>>(c2h, c2l, 128, wc2h, wc2l, bnc2, bufA);
    // fusion + heads
    heads<<<dim3(16, 8), blk, 0, stream>>>(bufD, bufA, Wout, bo, Wp3, bp3, Wc3, bc3, out);
}

// Round 4
// 757.563 us; speedup vs baseline: 1.2556x; 1.0159x over previous
//
#include <hip/hip_runtime.h>
#include <math.h>

// ---------------------------------------------------------------------------
// DAHead: B=8, Cin=512, Ci=128, H=W=64, N=4096, Ck=16, NC=19.
// R9: (a) conv kernels -> 1-output-row 256-thr 4-wave blocks, grid (64,2,8)
//     = 1024 blocks = 4 independent barrier domains/CU (same 16 waves/CU,
//     decoupled barriers). LDS 24.75KB/block. (b) pam_attn online softmax
//     (running max + acc rescale, cross-wave max via LDS) -> pam_rowmax
//     deleted (it was a full redundant QK^T pass).
// ws (byte offsets):
//   bufA@0 (16MB fp32)  bufB@16M (16MB fp32)
//   vb@32M (8MB bf16)   egy_part@40M (4MB fp32)   [both dead before conv2p]
//   bufD@32M (16MB fp32, conv2p out)
//   bh@48M, bl@56M (8MB bf16 each) -> pam_bf@48M -> c2h@48M, c2l@56M
//   qt@64M, kt@65M, egy@66M+128K
//   wp1@67M, wc1h, wc1l (1.125MB each), wp2, wc2h, wc2l (288KB each)
// ---------------------------------------------------------------------------

typedef __attribute__((ext_vector_type(8)))  short short8;
typedef __attribute__((ext_vector_type(16))) float f32x16;

__device__ inline unsigned short f2bf(float f) {
    union { float f; unsigned u; } v; v.f = f;
    unsigned r = v.u + 0x7fffu + ((v.u >> 16) & 1u);   // RNE
    return (unsigned short)(r >> 16);
}
__device__ inline float bf2f(unsigned short h) {
    union { unsigned u; float f; } v; v.u = ((unsigned)h) << 16;
    return v.f;
}

// ---- weight prepack: W[co][cin][9] fp32 ->
//      wpack[chunk][tap][g(=ci>>3)][co128][ci8]  (bf16) ----------------------
__global__ __launch_bounds__(256) void wpack_kernel(
    const float* __restrict__ W, unsigned short* __restrict__ wp, int Cin, int total)
{
    int idx = blockIdx.x * 256 + threadIdx.x;
    if (idx >= total) return;
    int chunk = idx / 18432;
    int rem   = idx - chunk * 18432;
    int tap   = rem >> 11;
    int rem2  = rem & 2047;
    int g     = rem2 >> 10;
    int co    = (rem2 >> 3) & 127;
    int ci8   = rem2 & 7;
    int cin   = (chunk << 4) + (g << 3) + ci8;
    wp[idx] = f2bf(W[((size_t)co * Cin + cin) * 9 + tap]);
}

__global__ __launch_bounds__(256) void wpack_split_kernel(
    const float* __restrict__ W, unsigned short* __restrict__ wph,
    unsigned short* __restrict__ wpl, int Cin, int total)
{
    int idx = blockIdx.x * 256 + threadIdx.x;
    if (idx >= total) return;
    int chunk = idx / 18432;
    int rem   = idx - chunk * 18432;
    int tap   = rem >> 11;
    int rem2  = rem & 2047;
    int g     = rem2 >> 10;
    int co    = (rem2 >> 3) & 127;
    int ci8   = rem2 & 7;
    int cin   = (chunk << 4) + (g << 3) + ci8;
    float w = W[((size_t)co * Cin + cin) * 9 + tap];
    unsigned short hi = f2bf(w);
    wph[idx] = hi;
    wpl[idx] = f2bf(w - bf2f(hi));
}

// ---- FUSED conv1: plain (Wp1 -> bufA) + hilo (Wc1 -> bufB,bh,bl) ----------
// 256 thr / 4 waves; 1 output row/block; wave tile 32px x 32co.
// grid (64, 2, 8) = 1024 blocks (4/CU). LDS 25344 B.
__global__ __launch_bounds__(256, 4) void conv3x3_merged(
    const float* __restrict__ xin,
    const unsigned short* __restrict__ wpp,
    const unsigned short* __restrict__ wph, const unsigned short* __restrict__ wpl,
    const float* __restrict__ bnp, const float* __restrict__ bnc,
    float* __restrict__ outP, float* __restrict__ outC,
    unsigned short* __restrict__ outh, unsigned short* __restrict__ outl)
{
    const int t   = threadIdx.x;
    const int w2  = t >> 6;           // 0..3
    const int xh  = w2 & 1;           // x half
    const int wy  = w2 >> 1;          // co 32-half
    const int ln  = t & 63;
    const int l31 = ln & 31;
    const int g   = ln >> 5;
    const int y   = blockIdx.x;       // output row
    const int co0 = blockIdx.y << 6;
    const int b   = blockIdx.z;

    // staging: t<192 -> one position (3 rows x 64 px), 16 channels each
    const int sr   = t >> 6;          // 0..2
    const int sx   = t & 63;
    const int sgy  = y - 1 + sr;
    const bool sv  = (t < 192) && ((unsigned)sgy < 64u);
    const int spid = sr * 66 + sx + 1;

    __shared__ __align__(16) unsigned short Xh[2][3168];   // [buf][g*1584 + pid*8]
    __shared__ __align__(16) unsigned short Xo[2][3168];   // 25344 B total

    for (int i = t; i < 792; i += 256) {
        uint4 z; z.x = 0; z.y = 0; z.z = 0; z.w = 0;
        ((uint4*)Xh)[i] = z;
        ((uint4*)Xo)[i] = z;
    }

    const int co = co0 + (wy << 5) + l31;
    const unsigned short* wPb = wpp + (size_t)(g << 10) + ((size_t)co << 3);
    const unsigned short* wHb = wph + (size_t)(g << 10) + ((size_t)co << 3);
    const unsigned short* wLb = wpl + (size_t)(g << 10) + ((size_t)co << 3);
    const float* xsrc = xin + ((size_t)b << 21) + (sgy << 6) + sx;

    const f32x16 zero = {0,0,0,0,0,0,0,0,0,0,0,0,0,0,0,0};
    f32x16 ap = zero, ac = zero;

    float xv[16];
    if (sv) {
#pragma unroll
        for (int c = 0; c < 16; c++) xv[c] = xsrc[(size_t)c << 12];
    }
    __syncthreads();   // zero-init done

    if (sv) {
        unsigned short th[16], tl[16];
#pragma unroll
        for (int c = 0; c < 16; c++) {
            unsigned short hi = f2bf(xv[c]);
            th[c] = hi; tl[c] = f2bf(xv[c] - bf2f(hi));
        }
        *(uint4*)&Xh[0][spid << 3]          = ((uint4*)th)[0];
        *(uint4*)&Xh[0][1584 + (spid << 3)] = ((uint4*)th)[1];
        *(uint4*)&Xo[0][spid << 3]          = ((uint4*)tl)[0];
        *(uint4*)&Xo[0][1584 + (spid << 3)] = ((uint4*)tl)[1];
    }

    int cur = 0;
    for (int ch = 0; ch < 32; ++ch) {
        __syncthreads();
        const bool pf = (ch < 31);
        if (pf && sv) {
#pragma unroll
            for (int c = 0; c < 16; c++)
                xv[c] = xsrc[((size_t)(ch + 1) << 16) + ((size_t)c << 12)];
        }
        const size_t wo = (size_t)ch * 18432;
#pragma unroll 3
        for (int tap = 0; tap < 9; ++tap) {
            const int dy = tap / 3, dx = tap - dy * 3;
            const int xi = (g ? 1584 : 0) + (((dy * 66) + (xh << 5) + l31 + dx) << 3);
            short8 vap = *(const short8*)(wPb + wo + tap * 2048);
            short8 vah = *(const short8*)(wHb + wo + tap * 2048);
            short8 val = *(const short8*)(wLb + wo + tap * 2048);
            short8 bh_ = *(const short8*)&Xh[cur][xi];
            short8 bl_ = *(const short8*)&Xo[cur][xi];
            ap = __builtin_amdgcn_mfma_f32_32x32x16_bf16(vap, bh_, ap, 0, 0, 0);
            ac = __builtin_amdgcn_mfma_f32_32x32x16_bf16(vah, bh_, ac, 0, 0, 0);
            ac = __builtin_amdgcn_mfma_f32_32x32x16_bf16(vah, bl_, ac, 0, 0, 0);
            ac = __builtin_amdgcn_mfma_f32_32x32x16_bf16(val, bh_, ac, 0, 0, 0);
        }
        if (pf && sv) {
            unsigned short th[16], tl[16];
#pragma unroll
            for (int c = 0; c < 16; c++) {
                unsigned short hi = f2bf(xv[c]);
                th[c] = hi; tl[c] = f2bf(xv[c] - bf2f(hi));
            }
            const int nb = cur ^ 1;
            *(uint4*)&Xh[nb][spid << 3]          = ((uint4*)th)[0];
            *(uint4*)&Xh[nb][1584 + (spid << 3)] = ((uint4*)th)[1];
            *(uint4*)&Xo[nb][spid << 3]          = ((uint4*)tl)[0];
            *(uint4*)&Xo[nb][1584 + (spid << 3)] = ((uint4*)tl)[1];
        }
        cur ^= 1;
    }

    const int x = (xh << 5) + l31;
#pragma unroll
    for (int r = 0; r < 16; r++) {
        int c2 = co0 + (wy << 5) + (r & 3) + ((r >> 2) << 3) + (g << 2);
        size_t o = (((size_t)b * 128 + c2) << 12) + (y << 6) + x;
        float vp = fmaf(ap[r], bnp[c2], bnp[128 + c2]);
        vp = vp > 0.f ? vp : 0.f;
        outP[o] = vp;
        float vc = fmaf(ac[r], bnc[c2], bnc[128 + c2]);
        vc = vc > 0.f ? vc : 0.f;
        outC[o] = vc;
        unsigned short hi = f2bf(vc);
        outh[o] = hi;
        outl[o] = f2bf(vc - bf2f(hi));
    }
}

// ---- plain 3x3 conv, bf16 input (conv2p). 256 thr, 1 row. grid (64,2,8) ---
__global__ __launch_bounds__(256, 4) void conv3x3_bf(
    const unsigned short* __restrict__ xin, int Cin,
    const unsigned short* __restrict__ wpk, const float* __restrict__ bn,
    float* __restrict__ out_f32)
{
    const int t   = threadIdx.x;
    const int w2  = t >> 6;
    const int xh  = w2 & 1;
    const int wy  = w2 >> 1;
    const int ln  = t & 63;
    const int l31 = ln & 31;
    const int g   = ln >> 5;
    const int y   = blockIdx.x;
    const int co0 = blockIdx.y << 6;
    const int b   = blockIdx.z;

    const int sr   = t >> 6;
    const int sx   = t & 63;
    const int sgy  = y - 1 + sr;
    const bool sv  = (t < 192) && ((unsigned)sgy < 64u);
    const int spid = sr * 66 + sx + 1;

    __shared__ __align__(16) unsigned short Xl[2][3168];   // 12672 B

    for (int i = t; i < 792; i += 256) {
        uint4 z; z.x = 0; z.y = 0; z.z = 0; z.w = 0;
        ((uint4*)Xl)[i] = z;
    }

    const int co = co0 + (wy << 5) + l31;
    const unsigned short* wB = wpk + (size_t)(g << 10) + ((size_t)co << 3);
    const unsigned short* xsrc = xin + (((size_t)b * Cin) << 12) + (sgy << 6) + sx;

    const f32x16 zero = {0,0,0,0,0,0,0,0,0,0,0,0,0,0,0,0};
    f32x16 acc = zero;

    unsigned short xv[16];
    if (sv) {
#pragma unroll
        for (int c = 0; c < 16; c++) xv[c] = xsrc[(size_t)c << 12];
    }
    __syncthreads();

    if (sv) {
        *(uint4*)&Xl[0][spid << 3]          = ((uint4*)xv)[0];
        *(uint4*)&Xl[0][1584 + (spid << 3)] = ((uint4*)xv)[1];
    }

    const int nchunks = Cin >> 4;
    int cur = 0;
    for (int ch = 0; ch < nchunks; ++ch) {
        __syncthreads();
        const bool pf = (ch < nchunks - 1);
        if (pf && sv) {
#pragma unroll
            for (int c = 0; c < 16; c++)
                xv[c] = xsrc[((size_t)(ch + 1) << 16) + ((size_t)c << 12)];
        }
        const size_t wo = (size_t)ch * 18432;
#pragma unroll 3
        for (int tap = 0; tap < 9; ++tap) {
            const int dy = tap / 3, dx = tap - dy * 3;
            const int xi = (g ? 1584 : 0) + (((dy * 66) + (xh << 5) + l31 + dx) << 3);
            short8 a  = *(const short8*)(wB + wo + tap * 2048);
            short8 b0 = *(const short8*)&Xl[cur][xi];
            acc = __builtin_amdgcn_mfma_f32_32x32x16_bf16(a, b0, acc, 0, 0, 0);
        }
        if (pf && sv) {
            const int nb = cur ^ 1;
            *(uint4*)&Xl[nb][spid << 3]          = ((uint4*)xv)[0];
            *(uint4*)&Xl[nb][1584 + (spid << 3)] = ((uint4*)xv)[1];
        }
        cur ^= 1;
    }

    const int x = (xh << 5) + l31;
#pragma unroll
    for (int r = 0; r < 16; r++) {
        int c2 = co0 + (wy << 5) + (r & 3) + ((r >> 2) << 3) + (g << 2);
        float v = fmaf(acc[r], bn[c2], bn[128 + c2]);
        v = v > 0.f ? v : 0.f;
        out_f32[(((size_t)b * 128 + c2) << 12) + (y << 6) + x] = v;
    }
}

// ---- hilo 3x3 conv, pre-split bf16 inputs (conv2c). 256 thr, 1 row. -------
__global__ __launch_bounds__(256, 4) void conv3x3_hilo_bf(
    const unsigned short* __restrict__ xhg, const unsigned short* __restrict__ xlg,
    int Cin, const unsigned short* __restrict__ wph, const unsigned short* __restrict__ wpl,
    const float* __restrict__ bn, float* __restrict__ out_f32)
{
    const int t   = threadIdx.x;
    const int w2  = t >> 6;
    const int xh  = w2 & 1;
    const int wy  = w2 >> 1;
    const int ln  = t & 63;
    const int l31 = ln & 31;
    const int g   = ln >> 5;
    const int y   = blockIdx.x;
    const int co0 = blockIdx.y << 6;
    const int b   = blockIdx.z;

    const int sr   = t >> 6;
    const int sx   = t & 63;
    const int sgy  = y - 1 + sr;
    const bool sv  = (t < 192) && ((unsigned)sgy < 64u);
    const int spid = sr * 66 + sx + 1;

    __shared__ __align__(16) unsigned short Xh[2][3168];
    __shared__ __align__(16) unsigned short Xo[2][3168];   // 25344 B

    for (int i = t; i < 792; i += 256) {
        uint4 z; z.x = 0; z.y = 0; z.z = 0; z.w = 0;
        ((uint4*)Xh)[i] = z;
        ((uint4*)Xo)[i] = z;
    }

    const int co = co0 + (wy << 5) + l31;
    const unsigned short* wHb = wph + (size_t)(g << 10) + ((size_t)co << 3);
    const unsigned short* wLb = wpl + (size_t)(g << 10) + ((size_t)co << 3);
    const unsigned short* hsrc = xhg + (((size_t)b * Cin) << 12) + (sgy << 6) + sx;
    const unsigned short* lsrc = xlg + (((size_t)b * Cin) << 12) + (sgy << 6) + sx;

    const f32x16 zero = {0,0,0,0,0,0,0,0,0,0,0,0,0,0,0,0};
    f32x16 acc = zero;

    unsigned short hv[16], lv[16];
    if (sv) {
#pragma unroll
        for (int c = 0; c < 16; c++) { hv[c] = hsrc[(size_t)c << 12]; lv[c] = lsrc[(size_t)c << 12]; }
    }
    __syncthreads();

    if (sv) {
        *(uint4*)&Xh[0][spid << 3]          = ((uint4*)hv)[0];
        *(uint4*)&Xh[0][1584 + (spid << 3)] = ((uint4*)hv)[1];
        *(uint4*)&Xo[0][spid << 3]          = ((uint4*)lv)[0];
        *(uint4*)&Xo[0][1584 + (spid << 3)] = ((uint4*)lv)[1];
    }

    const int nchunks = Cin >> 4;
    int cur = 0;
    for (int ch = 0; ch < nchunks; ++ch) {
        __syncthreads();
        const bool pf = (ch < nchunks - 1);
        if (pf && sv) {
#pragma unroll
            for (int c = 0; c < 16; c++) {
                hv[c] = hsrc[((size_t)(ch + 1) << 16) + ((size_t)c << 12)];
                lv[c] = lsrc[((size_t)(ch + 1) << 16) + ((size_t)c << 12)];
            }
        }
        const size_t wo = (size_t)ch * 18432;
#pragma unroll 3
        for (int tap = 0; tap < 9; ++tap) {
            const int dy = tap / 3, dx = tap - dy * 3;
            const int xi = (g ? 1584 : 0) + (((dy * 66) + (xh << 5) + l31 + dx) << 3);
            short8 ah  = *(const short8*)(wHb + wo + tap * 2048);
            short8 al  = *(const short8*)(wLb + wo + tap * 2048);
            short8 bh_ = *(const short8*)&Xh[cur][xi];
            short8 bl_ = *(const short8*)&Xo[cur][xi];
            acc = __builtin_amdgcn_mfma_f32_32x32x16_bf16(ah, bh_, acc, 0, 0, 0);
            acc = __builtin_amdgcn_mfma_f32_32x32x16_bf16(ah, bl_, acc, 0, 0, 0);
            acc = __builtin_amdgcn_mfma_f32_32x32x16_bf16(al, bh_, acc, 0, 0, 0);
        }
        if (pf && sv) {
            const int nb = cur ^ 1;
            *(uint4*)&Xh[nb][spid << 3]          = ((uint4*)hv)[0];
            *(uint4*)&Xh[nb][1584 + (spid << 3)] = ((uint4*)hv)[1];
            *(uint4*)&Xo[nb][spid << 3]          = ((uint4*)lv)[0];
            *(uint4*)&Xo[nb][1584 + (spid << 3)] = ((uint4*)lv)[1];
        }
        cur ^= 1;
    }

    const int x = (xh << 5) + l31;
#pragma unroll
    for (int r = 0; r < 16; r++) {
        int c2 = co0 + (wy << 5) + (r & 3) + ((r >> 2) << 3) + (g << 2);
        float v = fmaf(acc[r], bn[c2], bn[128 + c2]);
        v = v > 0.f ? v : 0.f;
        out_f32[(((size_t)b * 128 + c2) << 12) + (y << 6) + x] = v;
    }
}

// ---- CAM Gram via hi/lo MFMA, n-split partials. grid (16, 8, 8) -----------
__global__ __launch_bounds__(256) void cam_energy_mfma(
    const unsigned short* __restrict__ bh, const unsigned short* __restrict__ bl,
    float* __restrict__ egy_part)
{
    const int t   = threadIdx.x;
    const int w   = t >> 6;
    const int ln  = t & 63;
    const int l31 = ln & 31;
    const int g   = ln >> 5;
    const int i0  = (blockIdx.x >> 2) << 5;
    const int j0  = (blockIdx.x & 3) << 5;
    const int nseg = blockIdx.y;
    const int b   = blockIdx.z;

    __shared__ float red[4][64][17];

    const f32x16 zero = {0,0,0,0,0,0,0,0,0,0,0,0,0,0,0,0};
    f32x16 acc = zero;
    const int nb = (nseg << 9) + (w << 7) + (g << 3);
    const size_t ri = ((size_t)b * 128 + i0 + l31) << 12;
    const size_t rj = ((size_t)b * 128 + j0 + l31) << 12;

#pragma unroll
    for (int c = 0; c < 8; c++) {
        const int n0 = nb + (c << 4);
        short8 ah  = *(const short8*)(bh + ri + n0);
        short8 al  = *(const short8*)(bl + ri + n0);
        short8 bhf = *(const short8*)(bh + rj + n0);
        short8 blf = *(const short8*)(bl + rj + n0);
        acc = __builtin_amdgcn_mfma_f32_32x32x16_bf16(ah, bhf, acc, 0, 0, 0);
        acc = __builtin_amdgcn_mfma_f32_32x32x16_bf16(ah, blf, acc, 0, 0, 0);
        acc = __builtin_amdgcn_mfma_f32_32x32x16_bf16(al, bhf, acc, 0, 0, 0);
    }
#pragma unroll
    for (int r = 0; r < 16; r++) red[w][ln][r] = acc[r];
    __syncthreads();

    const int lane = t & 63;
    const int rq   = t >> 6;
    float* base = egy_part + (((size_t)(nseg * 8 + b)) << 14);
#pragma unroll
    for (int e = 0; e < 4; e++) {
        const int reg = (rq << 2) + e;
        float v = red[0][lane][reg] + red[1][lane][reg]
                + red[2][lane][reg] + red[3][lane][reg];
        const int i = i0 + (reg & 3) + ((reg >> 2) << 3) + ((lane >> 5) << 2);
        base[i * 128 + j0 + (lane & 31)] = v;
    }
}

// ---- CAM softmax of (rowmax - e), fused 8-seg reduce. grid (8, 8) ---------
__global__ __launch_bounds__(256) void cam_softmax_fused(
    const float* __restrict__ egy_part, float* __restrict__ egy)
{
    const int b   = blockIdx.x;
    const int rg  = blockIdx.y;
    const int t   = threadIdx.x;
    const int row = (rg << 4) + (t >> 4);
    const int jg  = t & 15;

    float e[8];
#pragma unroll
    for (int jj = 0; jj < 8; jj++) e[jj] = 0.f;
    for (int seg = 0; seg < 8; seg++) {
        const float* p = egy_part + (((size_t)(seg * 8 + b)) << 14) + row * 128 + (jg << 3);
#pragma unroll
        for (int jj = 0; jj < 8; jj++) e[jj] += p[jj];
    }
    float mn = e[0];
#pragma unroll
    for (int jj = 1; jj < 8; jj++) mn = fminf(mn, e[jj]);
#pragma unroll
    for (int k = 1; k < 16; k <<= 1) mn = fminf(mn, __shfl_xor(mn, k));
    float s = 0.f;
#pragma unroll
    for (int jj = 0; jj < 8; jj++) { float p = __expf(mn - e[jj]); e[jj] = p; s += p; }
#pragma unroll
    for (int k = 1; k < 16; k <<= 1) s += __shfl_xor(s, k);
    const float inv = 1.f / s;
    float* orow = egy + ((size_t)b << 14) + row * 128 + (jg << 3);
#pragma unroll
    for (int jj = 0; jj < 8; jj++) orow[jj] = e[jj] * inv;
}

// ---- PAM Q/K producer ----
__global__ __launch_bounds__(256) void pam_qk_1x1(
    const float* __restrict__ A, const float* __restrict__ Wb, const float* __restrict__ bb,
    const float* __restrict__ Wc, const float* __restrict__ bc,
    unsigned short* __restrict__ qt, unsigned short* __restrict__ kt)
{
    __shared__ float wl[2 * 16 * 128];
    __shared__ float bl[32];
    const int t = threadIdx.x;
    const int n = (blockIdx.x << 8) + t;
    const int b = blockIdx.y;
    for (int idx = t; idx < 2048; idx += 256) { wl[idx] = Wb[idx]; wl[2048 + idx] = Wc[idx]; }
    if (t < 16) { bl[t] = bb[t]; bl[16 + t] = bc[t]; }
    __syncthreads();
    float ab[16], ac[16];
#pragma unroll
    for (int k = 0; k < 16; k++) { ab[k] = 0.f; ac[k] = 0.f; }
    for (int chn = 0; chn < 128; ++chn) {
        float a = A[(((size_t)b * 128 + chn) << 12) + n];
#pragma unroll
        for (int k = 0; k < 16; k++) {
            ab[k] = fmaf(wl[k * 128 + chn], a, ab[k]);
            ac[k] = fmaf(wl[2048 + k * 128 + chn], a, ac[k]);
        }
    }
    unsigned short uq[16], uk[16];
#pragma unroll
    for (int k = 0; k < 16; k++) {
        uq[k] = f2bf(ab[k] + bl[k]);
        uk[k] = f2bf(ac[k] + bl[16 + k]);
    }
    size_t row = (size_t)b * 4096 + n;
    ((uint4*)qt)[row * 2 + 0] = ((uint4*)uq)[0];
    ((uint4*)qt)[row * 2 + 1] = ((uint4*)uq)[1];
    ((uint4*)kt)[row * 2 + 0] = ((uint4*)uk)[0];
    ((uint4*)kt)[row * 2 + 1] = ((uint4*)uk)[1];
}

// ---- PAM V producer ----
__global__ __launch_bounds__(256) void pam_v_1x1(
    const float* __restrict__ A, const float* __restrict__ Wd, const float* __restrict__ bd,
    unsigned short* __restrict__ vb)
{
    __shared__ float wl[32 * 128];
    __shared__ float bl[32];
    const int t   = threadIdx.x;
    const int n   = (blockIdx.x << 8) + t;
    const int co0 = blockIdx.y << 5;
    const int b   = blockIdx.z;
    for (int idx = t; idx < 4096; idx += 256) {
        int c2 = idx >> 7, chv = idx & 127;
        wl[idx] = Wd[(co0 + c2) * 128 + chv];
    }
    if (t < 32) bl[t] = bd[co0 + t];
    __syncthreads();
    float acc[32];
#pragma unroll
    for (int k = 0; k < 32; k++) acc[k] = 0.f;
    for (int chn = 0; chn < 128; ++chn) {
        float a = A[(((size_t)b * 128 + chn) << 12) + n];
#pragma unroll
        for (int k = 0; k < 32; k++) acc[k] = fmaf(wl[k * 128 + chn], a, acc[k]);
    }
#pragma unroll
    for (int k = 0; k < 32; k++)
        vb[(((size_t)b * 128 + co0 + k) << 12) + n] = f2bf(acc[k] + bl[k]);
}

// ---- PAM attention, MFMA, ONLINE softmax (no precomputed rowmax) ----------
__global__ __launch_bounds__(256) void pam_attn_mfma(
    const unsigned short* __restrict__ qt, const unsigned short* __restrict__ kt,
    const unsigned short* __restrict__ vb,
    const float* __restrict__ alpha, const float* __restrict__ Y,
    unsigned short* __restrict__ outb)
{
    const int t  = threadIdx.x;
    const int w  = t >> 6;
    const int L  = t & 63;
    const int ln = L & 31;
    const int g  = L >> 5;
    const int b  = blockIdx.y;
    const int n0 = blockIdx.x << 5;
    const int c0 = w << 5;

    __shared__ unsigned short Pf[16 * 256];
    __shared__ float red[4][32];

    const f32x16 zero = {0,0,0,0,0,0,0,0,0,0,0,0,0,0,0,0};
    short8 qfrag = *(const short8*)(qt + (((size_t)b * 4096 + n0 + ln) << 4) + (g << 3));
    const float al = alpha[0];

    f32x16 acc = zero;
    float rs = 0.f;
    float mold = -3.0e38f;

    for (int m0 = 0; m0 < 4096; m0 += 128) {
        const int mq = m0 + (w << 5);
        short8 kfrag = *(const short8*)(kt + (((size_t)b * 4096 + mq + ln) << 4) + (g << 3));
        f32x16 s = __builtin_amdgcn_mfma_f32_32x32x16_bf16(kfrag, qfrag, zero, 0, 0, 0);

        // per-row (n) running max across the 128-m block
        float lm = s[0];
#pragma unroll
        for (int r = 1; r < 16; r++) lm = fmaxf(lm, s[r]);
        lm = fmaxf(lm, __shfl_xor(lm, 32));
        if (L < 32) red[w][L] = lm;
        __syncthreads();
        const float mb = fmaxf(fmaxf(red[0][ln], red[1][ln]),
                               fmaxf(red[2][ln], red[3][ln]));
        const float mnew = fmaxf(mold, mb);
        const float fs = __expf(mold - mnew);
        mold = mnew;
        rs *= fs;
#pragma unroll
        for (int r = 0; r < 16; r++) acc[r] *= fs;

        float p[16];
#pragma unroll
        for (int r = 0; r < 16; r++) { p[r] = __expf(s[r] - mnew); rs += p[r]; }
        float xx[16];
#pragma unroll
        for (int r = 0; r < 16; r++) xx[r] = __shfl_xor(p[r], 32);

        unsigned short f0[8], f1[8];
#pragma unroll
        for (int i = 0; i < 4; i++) {
            f0[i]     = f2bf(g ? xx[4 + i]  : p[i]);
            f0[4 + i] = f2bf(g ? p[4 + i]   : xx[i]);
            f1[i]     = f2bf(g ? xx[12 + i] : p[8 + i]);
            f1[4 + i] = f2bf(g ? p[12 + i]  : xx[8 + i]);
        }
        *(short8*)(&Pf[((w << 2) + g) * 256 + (ln << 3)])     = *(short8*)f0;
        *(short8*)(&Pf[((w << 2) + 2 + g) * 256 + (ln << 3)]) = *(short8*)f1;
        __syncthreads();

#pragma unroll
        for (int kk = 0; kk < 8; kk++) {
            short8 pfrag = *(const short8*)(&Pf[((kk << 1) + g) * 256 + (ln << 3)]);
            short8 vfrag = *(const short8*)(vb + (((size_t)b * 128 + c0 + ln) << 12)
                                               + m0 + (kk << 4) + (g << 3));
            acc = __builtin_amdgcn_mfma_f32_32x32x16_bf16(vfrag, pfrag, acc, 0, 0, 0);
        }
        __syncthreads();
    }

    rs += __shfl_xor(rs, 32);
    if (L < 32) red[w][L] = rs;
    __syncthreads();
    const float inv = 1.f / (red[0][ln] + red[1][ln] + red[2][ln] + red[3][ln]);
    const int n = n0 + ln;
#pragma unroll
    for (int r = 0; r < 16; r++) {
        int c = c0 + (r & 3) + ((r >> 2) << 3) + (g << 2);
        size_t idx = (((size_t)b * 128 + c) << 12) + n;
        outb[idx] = f2bf(fmaf(al, acc[r] * inv, Y[idx]));
    }
}

// ---- CAM feat: emits hi/lo bf16 directly (feeds conv2c) -------------------
__global__ __launch_bounds__(256) void cam_feat(
    const float* __restrict__ attn, const float* __restrict__ Bf,
    const float* __restrict__ beta, unsigned short* __restrict__ oh,
    unsigned short* __restrict__ ol)
{
    const int t  = threadIdx.x;
    const int n  = (blockIdx.x << 8) + t;
    const int c0 = blockIdx.y << 5;
    const int b  = blockIdx.z;
    __shared__ float al[32 * 128];
    for (int idx = t; idx < 4096; idx += 256)
        al[idx] = attn[(size_t)b * 16384 + (c0 + (idx >> 7)) * 128 + (idx & 127)];
    __syncthreads();
    float acc[32];
#pragma unroll
    for (int k = 0; k < 32; k++) acc[k] = 0.f;
    for (int d = 0; d < 128; ++d) {
        float v = Bf[(((size_t)b * 128 + d) << 12) + n];
#pragma unroll
        for (int k = 0; k < 32; k++) acc[k] = fmaf(al[k * 128 + d], v, acc[k]);
    }
    float be = beta[0];
#pragma unroll
    for (int k = 0; k < 32; k++) {
        size_t idx = (((size_t)b * 128 + c0 + k) << 12) + n;
        float v = fmaf(be, acc[k], Bf[idx]);
        unsigned short hi = f2bf(v);
        oh[idx] = hi;
        ol[idx] = f2bf(v - bf2f(hi));
    }
}

// ---- Final heads ----
__global__ __launch_bounds__(256) void heads(
    const float* __restrict__ FP, const float* __restrict__ FC,
    const float* __restrict__ Wout, const float* __restrict__ bout,
    const float* __restrict__ Wp3, const float* __restrict__ bp3,
    const float* __restrict__ Wc3, const float* __restrict__ bc3,
    float* __restrict__ out)
{
    const int t = threadIdx.x;
    const int n = (blockIdx.x << 8) + t;
    const int b = blockIdx.y;
    __shared__ float wl[3 * 19 * 128];
    __shared__ float bl[3 * 19];
    for (int idx = t; idx < 2432; idx += 256) {
        wl[idx]        = Wout[idx];
        wl[2432 + idx] = Wp3[idx];
        wl[4864 + idx] = Wc3[idx];
    }
    if (t < 19) { bl[t] = bout[t]; bl[19 + t] = bp3[t]; bl[38 + t] = bc3[t]; }
    __syncthreads();
    float am[19], ap[19], ac[19];
#pragma unroll
    for (int o = 0; o < 19; o++) { am[o] = 0.f; ap[o] = 0.f; ac[o] = 0.f; }
    for (int chn = 0; chn < 128; ++chn) {
        float pv = FP[(((size_t)b * 128 + chn) << 12) + n];
        float cv = FC[(((size_t)b * 128 + chn) << 12) + n];
        float fv = pv + cv;
#pragma unroll
        for (int o = 0; o < 19; o++) {
            am[o] = fmaf(wl[o * 128 + chn], fv, am[o]);
            ap[o] = fmaf(wl[2432 + o * 128 + chn], pv, ap[o]);
            ac[o] = fmaf(wl[4864 + o * 128 + chn], cv, ac[o]);
        }
    }
    const size_t OS = (size_t)8 * 19 * 4096;
#pragma unroll
    for (int o = 0; o < 19; o++) {
        size_t base = (((size_t)b * 19 + o) << 12) + n;
        out[base]          = 1.f / (1.f + __expf(-(am[o] + bl[o])));
        out[OS + base]     = 1.f / (1.f + __expf(-(ap[o] + bl[19 + o])));
        out[2 * OS + base] = 1.f / (1.f + __expf(-(ac[o] + bl[38 + o])));
    }
}

extern "C" void kernel_launch(void* const* d_in, const int* in_sizes, int n_in,
                              void* d_out, int out_size, void* d_ws, size_t ws_size,
                              hipStream_t stream)
{
    const float* x     = (const float*)d_in[0];
    const float* Wp1   = (const float*)d_in[1];
    const float* bnp1  = (const float*)d_in[2];
    const float* Wc1   = (const float*)d_in[3];
    const float* bnc1  = (const float*)d_in[4];
    const float* Wb    = (const float*)d_in[5];
    const float* bb    = (const float*)d_in[6];
    const float* Wc    = (const float*)d_in[7];
    const float* bcv   = (const float*)d_in[8];
    const float* Wd    = (const float*)d_in[9];
    const float* bd    = (const float*)d_in[10];
    const float* alpha = (const float*)d_in[11];
    const float* beta  = (const float*)d_in[12];
    const float* Wp2   = (const float*)d_in[13];
    const float* bnp2  = (const float*)d_in[14];
    const float* Wc2   = (const float*)d_in[15];
    const float* bnc2  = (const float*)d_in[16];
    const float* Wout  = (const float*)d_in[17];
    const float* bo    = (const float*)d_in[18];
    const float* Wp3   = (const float*)d_in[19];
    const float* bp3   = (const float*)d_in[20];
    const float* Wc3   = (const float*)d_in[21];
    const float* bc3   = (const float*)d_in[22];
    float* out = (float*)d_out;

    char* ws = (char*)d_ws;
    const size_t MB = 1u << 20;
    const size_t W1SZ = (size_t)32 * 18432 * 2;
    const size_t W2SZ = (size_t)8 * 18432 * 2;
    float*          bufA     = (float*)(ws);
    float*          bufB     = (float*)(ws + 16 * MB);
    unsigned short* vb       = (unsigned short*)(ws + 32 * MB);  // 8MB
    float*          egy_part = (float*)(ws + 40 * MB);           // 4MB
    float*          bufD     = (float*)(ws + 32 * MB);           // conv2p out (later)
    unsigned short* bh       = (unsigned short*)(ws + 48 * MB);  // 8MB
    unsigned short* blo      = (unsigned short*)(ws + 56 * MB);  // 8MB
    unsigned short* pam_bf   = (unsigned short*)(ws + 48 * MB);  // after Gram
    unsigned short* c2h      = (unsigned short*)(ws + 48 * MB);  // after conv2p
    unsigned short* c2l      = (unsigned short*)(ws + 56 * MB);
    unsigned short* qt       = (unsigned short*)(ws + 64 * MB);
    unsigned short* kt       = (unsigned short*)(ws + 65 * MB);
    float*          egy      = (float*)(ws + 66 * MB + (1u << 17));
    unsigned short* wp1      = (unsigned short*)(ws + 67 * MB);
    unsigned short* wc1h     = (unsigned short*)(ws + 67 * MB + W1SZ);
    unsigned short* wc1l     = (unsigned short*)(ws + 67 * MB + 2 * W1SZ);
    unsigned short* wp2      = (unsigned short*)(ws + 67 * MB + 3 * W1SZ);
    unsigned short* wc2h     = (unsigned short*)(ws + 67 * MB + 3 * W1SZ + W2SZ);
    unsigned short* wc2l     = (unsigned short*)(ws + 67 * MB + 3 * W1SZ + 2 * W2SZ);

    dim3 blk(256);
    const int n1 = 32 * 18432;
    const int n2 = 8 * 18432;
    wpack_kernel<<<dim3((n1 + 255) / 256), blk, 0, stream>>>(Wp1, wp1, 512, n1);
    wpack_kernel<<<dim3((n2 + 255) / 256), blk, 0, stream>>>(Wp2, wp2, 128, n2);
    wpack_split_kernel<<<dim3((n1 + 255) / 256), blk, 0, stream>>>(Wc1, wc1h, wc1l, 512, n1);
    wpack_split_kernel<<<dim3((n2 + 255) / 256), blk, 0, stream>>>(Wc2, wc2h, wc2l, 128, n2);

    // fused conv1p + conv1c (shared hi/lo X staging, dbuf, W in regs, 1-row blocks)
    conv3x3_merged<<<dim3(64, 2, 8), blk, 0, stream>>>(x, wp1, wc1h, wc1l, bnp1, bnc1,
                                                       bufA, bufB, bh, blo);
    // CAM Gram + softmax (consumes bh/bl, egy_part)
    cam_energy_mfma<<<dim3(16, 8, 8), blk, 0, stream>>>(bh, blo, egy_part);
    cam_softmax_fused<<<dim3(8, 8), blk, 0, stream>>>(egy_part, egy);
    // PAM
    pam_qk_1x1<<<dim3(16, 8), blk, 0, stream>>>(bufA, Wb, bb, Wc, bcv, qt, kt);
    pam_v_1x1<<<dim3(16, 4, 8), blk, 0, stream>>>(bufA, Wd, bd, vb);
    pam_attn_mfma<<<dim3(128, 8), blk, 0, stream>>>(qt, kt, vb, alpha, bufA, pam_bf);
    // conv2p (reads pam_bf, writes bufD over vb/egy_part which are now dead)
    conv3x3_bf<<<dim3(64, 2, 8), blk, 0, stream>>>(pam_bf, 128, wp2, bnp2, bufD);
    // CAM tail (c2h/c2l overwrite pam_bf region after conv2p consumed it)
    cam_feat<<<dim3(16, 4, 8), blk, 0, stream>>>(egy, bufB, beta, c2h, c2l);
    conv3x3_hilo_bf<<<dim3(64, 2, 8), blk, 0, stream>>>(c2h, c2l, 128, wc2h, wc2l, bnc2, bufA);
    // fusion + heads
    heads<<<dim3(16, 8), blk, 0, stream>>>(bufD, bufA, Wout, bo, Wp3, bp3, Wc3, bc3, out);
}